// Round 3
// baseline (607.375 us; speedup 1.0000x reference)
//
#include <hip/hip_runtime.h>
#include <hip/hip_bf16.h>

typedef __bf16 bf16x8 __attribute__((ext_vector_type(8)));
typedef float f32x4 __attribute__((ext_vector_type(4)));
using BF = __hip_bfloat16;

// Problem constants
constexpr int B_   = 2;
constexpr int S_   = 2048;
constexpr int NH_  = 16;
constexpr int HD_  = 128;
constexpr int HID_ = 2048;
constexpr int CKV_ = 512;
constexpr int CQ_  = 1024;
constexpr int RD_  = 64;
constexpr int M_   = B_ * S_;     // 4096 tokens
constexpr int DQK_ = HD_ + RD_;   // 192

__device__ __forceinline__ f32x4 mfma16(bf16x8 a, bf16x8 b, f32x4 c) {
  return __builtin_amdgcn_mfma_f32_16x16x32_bf16(a, b, c, 0, 0, 0);
}

// ---------------- fp32 -> bf16 convert (vectorized) ----------------
__global__ __launch_bounds__(256) void f2b_kern(const float* __restrict__ in,
                                                BF* __restrict__ out, int n4) {
  int i = blockIdx.x * 256 + threadIdx.x;
  if (i >= n4) return;
  float4 v = reinterpret_cast<const float4*>(in)[i];
  BF o[4] = {__float2bfloat16(v.x), __float2bfloat16(v.y),
             __float2bfloat16(v.z), __float2bfloat16(v.w)};
  reinterpret_cast<uint2*>(out)[i] = *reinterpret_cast<uint2*>(o);
}

// ------------- tiled transpose fp32 (K,N) -> bf16 (Npad,K), zero-pad n>=N -------------
__global__ __launch_bounds__(256) void wtrans(const float* __restrict__ in,
                                              BF* __restrict__ out,
                                              int K, int N, int Npad) {
  __shared__ float t[32][33];
  int n0 = blockIdx.x * 32, k0 = blockIdx.y * 32;
  int tx = threadIdx.x, ty = threadIdx.y;
#pragma unroll
  for (int j = 0; j < 4; j++) {
    int k = k0 + ty + j * 8, n = n0 + tx;
    t[ty + j * 8][tx] = (n < N) ? in[(size_t)k * N + n] : 0.f;
  }
  __syncthreads();
#pragma unroll
  for (int j = 0; j < 4; j++) {
    int n = n0 + ty + j * 8, k = k0 + tx;
    out[(size_t)n * K + k] = __float2bfloat16(t[tx][ty + j * 8]);
  }
}

// ---------------- GEMM: C = A(M,K) x Bt(N,K)^T, bf16 in, fp32 acc ----------------
// 128x128 tile, BK=32, 256 threads = 4 waves (2x2), each wave 64x64 (4x4 frags).
// MODE 0: bf16 C[m*N + n]
// MODE 1: bf16 C[((b*16+h)*2048 + s)*192 + d]   (head scatter, d = n&127, h = n>>7)
// MODE 2: bf16 C[((b*16+h)*128 + d)*2048 + s]   (v^T scatter)
// MODE 3: fp32 C[m*N + n]
template <int MODE>
__global__ __launch_bounds__(256) void gemm_bt(const BF* __restrict__ A,
                                               const BF* __restrict__ Bt,
                                               void* __restrict__ C,
                                               int M, int N, int K) {
  __shared__ BF As[128][32];
  __shared__ BF Bs[128][32];
  const int tid = threadIdx.x;
  const int w = tid >> 6, l = tid & 63;
  const int lr = l & 15, lg = l >> 4;
  const int wr = w >> 1, wc = w & 1;
  const int m0 = blockIdx.y * 128, n0 = blockIdx.x * 128;

  f32x4 acc[4][4];
#pragma unroll
  for (int m = 0; m < 4; m++)
#pragma unroll
    for (int n = 0; n < 4; n++) acc[m][n] = (f32x4){0.f, 0.f, 0.f, 0.f};

  for (int k0 = 0; k0 < K; k0 += 32) {
    __syncthreads();
#pragma unroll
    for (int j = 0; j < 2; j++) {
      int idx = tid + j * 256;
      int row = idx >> 2, seg = idx & 3;
      *reinterpret_cast<bf16x8*>(&As[row][seg * 8]) =
          *reinterpret_cast<const bf16x8*>(A + (size_t)(m0 + row) * K + k0 + seg * 8);
      *reinterpret_cast<bf16x8*>(&Bs[row][seg * 8]) =
          *reinterpret_cast<const bf16x8*>(Bt + (size_t)(n0 + row) * K + k0 + seg * 8);
    }
    __syncthreads();
    bf16x8 af[4], bfr[4];
#pragma unroll
    for (int m = 0; m < 4; m++)
      af[m] = *reinterpret_cast<const bf16x8*>(&As[wr * 64 + m * 16 + lr][lg * 8]);
#pragma unroll
    for (int n = 0; n < 4; n++)
      bfr[n] = *reinterpret_cast<const bf16x8*>(&Bs[wc * 64 + n * 16 + lr][lg * 8]);
#pragma unroll
    for (int m = 0; m < 4; m++)
#pragma unroll
      for (int n = 0; n < 4; n++) acc[m][n] = mfma16(af[m], bfr[n], acc[m][n]);
  }

  // epilogue: C/D layout col = lane&15, row = (lane>>4)*4 + j  (m89-verified)
#pragma unroll
  for (int m = 0; m < 4; m++) {
#pragma unroll
    for (int n = 0; n < 4; n++) {
#pragma unroll
      for (int j = 0; j < 4; j++) {
        int row = m0 + wr * 64 + m * 16 + lg * 4 + j;
        int col = n0 + wc * 64 + n * 16 + lr;
        float v = acc[m][n][j];
        if constexpr (MODE == 0) {
          ((BF*)C)[(size_t)row * N + col] = __float2bfloat16(v);
        } else if constexpr (MODE == 1) {
          int b = row >> 11, s = row & 2047, h = col >> 7, d = col & 127;
          ((BF*)C)[((size_t)(b * 16 + h) * 2048 + s) * 192 + d] = __float2bfloat16(v);
        } else if constexpr (MODE == 2) {
          int b = row >> 11, s = row & 2047, h = col >> 7, d = col & 127;
          ((BF*)C)[((size_t)(b * 16 + h) * 128 + d) * 2048 + s] = __float2bfloat16(v);
        } else {
          ((float*)C)[(size_t)row * N + col] = v;
        }
      }
    }
  }
}

// ---------------- RoPE ----------------
__global__ __launch_bounds__(256) void rope_q(const BF* __restrict__ qr, BF* __restrict__ qb) {
  int idx = blockIdx.x * 256 + threadIdx.x;  // 4096*16*64
  int d = idx & 63, h = (idx >> 6) & 15, m = idx >> 10;
  int s = m & 2047, b = m >> 11;
  float x = __bfloat162float(qr[(size_t)(m << 10) + (h << 6) + d]);
  float other = __bfloat162float(qr[(size_t)(m << 10) + (h << 6) + (d ^ 32)]);
  float rot = (d < 32) ? -other : other;
  int di = d & 31;
  float arg = (float)s * powf(10000.f, -(float)di / 32.0f);
  float c = cosf(arg), sn = sinf(arg);
  qb[((size_t)(b * 16 + h) * 2048 + s) * 192 + 128 + d] = __float2bfloat16(x * c + rot * sn);
}

__global__ __launch_bounds__(256) void rope_k(const BF* __restrict__ kr, BF* __restrict__ kb) {
  int idx = blockIdx.x * 256 + threadIdx.x;  // 4096*64
  int d = idx & 63, m = idx >> 6;
  int s = m & 2047, b = m >> 11;
  float x = __bfloat162float(kr[(size_t)m * 128 + d]);
  float other = __bfloat162float(kr[(size_t)m * 128 + (d ^ 32)]);
  float rot = (d < 32) ? -other : other;
  int di = d & 31;
  float arg = (float)s * powf(10000.f, -(float)di / 32.0f);
  float val = x * cosf(arg) + rot * sinf(arg);
  BF v = __float2bfloat16(val);
#pragma unroll
  for (int h = 0; h < 16; h++)
    kb[((size_t)(b * 16 + h) * 2048 + s) * 192 + 128 + d] = v;
}

// ---------------- flash attention ----------------
// grid (S/64, B*NH), 256 threads = 4 waves; wave w owns q-rows [q0+16w, q0+16w+16)
__global__ __launch_bounds__(256) void attn_kern(const BF* __restrict__ qb,
                                                 const BF* __restrict__ kb,
                                                 const BF* __restrict__ vT,
                                                 BF* __restrict__ o) {
  const int bh = blockIdx.y;
  const int q0 = blockIdx.x * 64;
  const int tid = threadIdx.x;
  const int w = tid >> 6, l = tid & 63;
  const int lr = l & 15, lg = l >> 4;

  __shared__ BF Ks[32][200];      // 32 keys x 192 (pad 200)
  __shared__ BF Vs[128][40];      // 128 dims x 32 keys (pad 40)
  __shared__ BF Ps[4][16][40];    // per-wave P: 16 rows x 32 cols (pad 40)

  bf16x8 aq[6];
  const BF* qrow = qb + ((size_t)bh * 2048 + q0 + w * 16 + lr) * 192;
#pragma unroll
  for (int kk = 0; kk < 6; kk++)
    aq[kk] = *reinterpret_cast<const bf16x8*>(qrow + kk * 32 + lg * 8);

  f32x4 Oacc[8];
#pragma unroll
  for (int d = 0; d < 8; d++) Oacc[d] = (f32x4){0.f, 0.f, 0.f, 0.f};
  float mrow[4], lrow[4];
#pragma unroll
  for (int j = 0; j < 4; j++) { mrow[j] = -3e38f; lrow[j] = 0.f; }

  const float scale = 0.07216878364870323f;  // 1/sqrt(192)
  const int nch = (q0 + 64) >> 5;

  for (int ch = 0; ch < nch; ch++) {
    const int c0 = ch << 5;
    __syncthreads();
    // stage K tile (32x192)
#pragma unroll
    for (int j2 = 0; j2 < 3; j2++) {
      int idx = tid + j2 * 256;
      int row = idx / 24, seg = idx % 24;
      *reinterpret_cast<bf16x8*>(&Ks[row][seg * 8]) =
          *reinterpret_cast<const bf16x8*>(kb + ((size_t)bh * 2048 + c0 + row) * 192 + seg * 8);
    }
    // stage V^T tile (128x32)
#pragma unroll
    for (int j2 = 0; j2 < 2; j2++) {
      int idx = tid + j2 * 256;
      int row = idx >> 2, seg = idx & 3;
      *reinterpret_cast<bf16x8*>(&Vs[row][seg * 8]) =
          *reinterpret_cast<const bf16x8*>(vT + ((size_t)bh * 128 + row) * 2048 + c0 + seg * 8);
    }
    __syncthreads();

    // QK^T: S tile 16 rows x 32 cols as two 16x16 frags
    f32x4 sf[2];
#pragma unroll
    for (int half = 0; half < 2; half++) {
      sf[half] = (f32x4){0.f, 0.f, 0.f, 0.f};
#pragma unroll
      for (int kk = 0; kk < 6; kk++) {
        bf16x8 bfr = *reinterpret_cast<const bf16x8*>(&Ks[half * 16 + lr][kk * 32 + lg * 8]);
        sf[half] = mfma16(aq[kk], bfr, sf[half]);
      }
    }
    // scale + causal mask
#pragma unroll
    for (int half = 0; half < 2; half++) {
#pragma unroll
      for (int j = 0; j < 4; j++) {
        int rgj = q0 + w * 16 + lg * 4 + j;
        int cg = c0 + half * 16 + lr;
        float s = sf[half][j] * scale;
        sf[half][j] = (cg <= rgj) ? s : -1e30f;
      }
    }
    // online softmax (row reduce over 16 lanes in group)
#pragma unroll
    for (int j = 0; j < 4; j++) {
      float mx = fmaxf(sf[0][j], sf[1][j]);
#pragma unroll
      for (int t = 1; t < 16; t <<= 1) mx = fmaxf(mx, __shfl_xor(mx, t, 64));
      float mnew = fmaxf(mrow[j], mx);
      float corr = __expf(mrow[j] - mnew);
      float p0 = __expf(sf[0][j] - mnew);
      float p1 = __expf(sf[1][j] - mnew);
      float sum = p0 + p1;
#pragma unroll
      for (int t = 1; t < 16; t <<= 1) sum += __shfl_xor(sum, t, 64);
      lrow[j] = lrow[j] * corr + sum;
      mrow[j] = mnew;
#pragma unroll
      for (int d = 0; d < 8; d++) Oacc[d][j] *= corr;
      Ps[w][lg * 4 + j][lr] = __float2bfloat16(p0);
      Ps[w][lg * 4 + j][16 + lr] = __float2bfloat16(p1);
    }
    __syncthreads();  // conservative: ensure P visible before frag read
    // PV: O += P(16x32) x V(32x128)
    bf16x8 pf = *reinterpret_cast<const bf16x8*>(&Ps[w][lr][lg * 8]);
#pragma unroll
    for (int d = 0; d < 8; d++) {
      bf16x8 vf = *reinterpret_cast<const bf16x8*>(&Vs[d * 16 + lr][lg * 8]);
      Oacc[d] = mfma16(pf, vf, Oacc[d]);
    }
  }

  // epilogue
  const int b = bh >> 4, h = bh & 15;
#pragma unroll
  for (int j = 0; j < 4; j++) {
    float rinv = 1.0f / lrow[j];
    int srow = q0 + w * 16 + lg * 4 + j;
#pragma unroll
    for (int d = 0; d < 8; d++) {
      o[((size_t)(b * 2048 + srow)) * 2048 + h * 128 + d * 16 + lr] =
          __float2bfloat16(Oacc[d][j] * rinv);
    }
  }
}

extern "C" void kernel_launch(void* const* d_in, const int* in_sizes, int n_in,
                              void* d_out, int out_size, void* d_ws, size_t ws_size,
                              hipStream_t stream) {
  const float* hs   = (const float*)d_in[0];
  const float* wDKV = (const float*)d_in[2];
  const float* wUK  = (const float*)d_in[3];
  const float* wUV  = (const float*)d_in[4];
  const float* wDQ  = (const float*)d_in[5];
  const float* wUQ  = (const float*)d_in[6];
  const float* wQR  = (const float*)d_in[7];
  const float* wKR  = (const float*)d_in[8];
  const float* wO   = (const float*)d_in[9];
  float* out = (float*)d_out;

  char* ws = (char*)d_ws;
  size_t off = 0;
  auto alloc = [&](size_t bytes) -> char* {
    char* p = ws + off;
    off += (bytes + 255) & ~(size_t)255;
    return p;
  };
  BF* hsb   = (BF*)alloc((size_t)M_ * HID_ * 2);        // 4096x2048
  BF* tDKV  = (BF*)alloc((size_t)CKV_ * HID_ * 2);      // (512,2048)
  BF* tUK   = (BF*)alloc((size_t)(NH_*HD_) * CKV_ * 2); // (2048,512)
  BF* tUV   = (BF*)alloc((size_t)(NH_*HD_) * CKV_ * 2); // (2048,512)
  BF* tDQ   = (BF*)alloc((size_t)CQ_ * HID_ * 2);       // (1024,2048)
  BF* tUQ   = (BF*)alloc((size_t)(NH_*HD_) * CQ_ * 2);  // (2048,1024)
  BF* tQR   = (BF*)alloc((size_t)(NH_*RD_) * CQ_ * 2);  // (1024,1024)
  BF* tKR   = (BF*)alloc((size_t)128 * HID_ * 2);       // (128,2048) padded
  BF* tWO   = (BF*)alloc((size_t)HID_ * (NH_*HD_) * 2); // (2048,2048)
  BF* cKV   = (BF*)alloc((size_t)M_ * CKV_ * 2);
  BF* cQ    = (BF*)alloc((size_t)M_ * CQ_ * 2);
  BF* qbuf  = (BF*)alloc((size_t)B_ * NH_ * S_ * DQK_ * 2);
  BF* kbuf  = (BF*)alloc((size_t)B_ * NH_ * S_ * DQK_ * 2);
  BF* vTb   = (BF*)alloc((size_t)B_ * NH_ * HD_ * S_ * 2);
  BF* qRt   = (BF*)alloc((size_t)M_ * (NH_*RD_) * 2);
  BF* kRt   = (BF*)alloc((size_t)M_ * 128 * 2);
  BF* aout  = (BF*)alloc((size_t)M_ * (NH_*HD_) * 2);

  // 1. hidden -> bf16
  f2b_kern<<<(M_ * HID_ / 4 + 255) / 256, 256, 0, stream>>>(hs, hsb, M_ * HID_ / 4);

  // 2. weight transposes (fp32 (K,N) -> bf16 (Npad,K))
  dim3 tb(32, 8);
  wtrans<<<dim3(CKV_ / 32, HID_ / 32), tb, 0, stream>>>(wDKV, tDKV, HID_, CKV_, CKV_);
  wtrans<<<dim3((NH_*HD_) / 32, CKV_ / 32), tb, 0, stream>>>(wUK, tUK, CKV_, NH_*HD_, NH_*HD_);
  wtrans<<<dim3((NH_*HD_) / 32, CKV_ / 32), tb, 0, stream>>>(wUV, tUV, CKV_, NH_*HD_, NH_*HD_);
  wtrans<<<dim3(CQ_ / 32, HID_ / 32), tb, 0, stream>>>(wDQ, tDQ, HID_, CQ_, CQ_);
  wtrans<<<dim3((NH_*HD_) / 32, CQ_ / 32), tb, 0, stream>>>(wUQ, tUQ, CQ_, NH_*HD_, NH_*HD_);
  wtrans<<<dim3((NH_*RD_) / 32, CQ_ / 32), tb, 0, stream>>>(wQR, tQR, CQ_, NH_*RD_, NH_*RD_);
  wtrans<<<dim3(128 / 32, HID_ / 32), tb, 0, stream>>>(wKR, tKR, HID_, RD_, 128);
  wtrans<<<dim3((NH_*HD_) / 32, HID_ / 32), tb, 0, stream>>>(wO, tWO, HID_, NH_*HD_, NH_*HD_);

  // 3. projections
  gemm_bt<0><<<dim3(CKV_ / 128, M_ / 128), 256, 0, stream>>>(hsb, tDKV, cKV, M_, CKV_, HID_);
  gemm_bt<0><<<dim3(CQ_ / 128, M_ / 128), 256, 0, stream>>>(hsb, tDQ, cQ, M_, CQ_, HID_);
  gemm_bt<1><<<dim3((NH_*HD_) / 128, M_ / 128), 256, 0, stream>>>(cKV, tUK, kbuf, M_, NH_*HD_, CKV_);
  gemm_bt<2><<<dim3((NH_*HD_) / 128, M_ / 128), 256, 0, stream>>>(cKV, tUV, vTb, M_, NH_*HD_, CKV_);
  gemm_bt<1><<<dim3((NH_*HD_) / 128, M_ / 128), 256, 0, stream>>>(cQ, tUQ, qbuf, M_, NH_*HD_, CQ_);
  gemm_bt<0><<<dim3((NH_*RD_) / 128, M_ / 128), 256, 0, stream>>>(cQ, tQR, qRt, M_, NH_*RD_, CQ_);
  gemm_bt<0><<<dim3(128 / 128, M_ / 128), 256, 0, stream>>>(hsb, tKR, kRt, M_, 128, HID_);

  // 4. RoPE
  rope_q<<<(M_ * NH_ * RD_) / 256, 256, 0, stream>>>(qRt, qbuf);
  rope_k<<<(M_ * RD_) / 256, 256, 0, stream>>>(kRt, kbuf);

  // 5. attention
  attn_kern<<<dim3(S_ / 64, B_ * NH_), 256, 0, stream>>>(qbuf, kbuf, vTb, aout);

  // 6. output projection (fp32 out)
  gemm_bt<3><<<dim3((NH_*HD_) / 128, M_ / 128), 256, 0, stream>>>(aout, tWO, out, M_, NH_*HD_, HID_);
}

// Round 4
// 592.685 us; speedup vs baseline: 1.0248x; 1.0248x over previous
//
#include <hip/hip_runtime.h>
#include <hip/hip_bf16.h>

typedef __bf16 bf16x8 __attribute__((ext_vector_type(8)));
typedef float f32x4 __attribute__((ext_vector_type(4)));
using BF = __hip_bfloat16;

// Problem constants
constexpr int B_   = 2;
constexpr int S_   = 2048;
constexpr int NH_  = 16;
constexpr int HD_  = 128;
constexpr int HID_ = 2048;
constexpr int CKV_ = 512;
constexpr int CQ_  = 1024;
constexpr int RD_  = 64;
constexpr int M_   = B_ * S_;     // 4096 tokens
constexpr int DQK_ = HD_ + RD_;   // 192

__device__ __forceinline__ f32x4 mfma16(bf16x8 a, bf16x8 b, f32x4 c) {
  return __builtin_amdgcn_mfma_f32_16x16x32_bf16(a, b, c, 0, 0, 0);
}

// ---------------- fp32 -> bf16 convert (vectorized) ----------------
__global__ __launch_bounds__(256) void f2b_kern(const float* __restrict__ in,
                                                BF* __restrict__ out, int n4) {
  int i = blockIdx.x * 256 + threadIdx.x;
  if (i >= n4) return;
  float4 v = reinterpret_cast<const float4*>(in)[i];
  BF o[4] = {__float2bfloat16(v.x), __float2bfloat16(v.y),
             __float2bfloat16(v.z), __float2bfloat16(v.w)};
  reinterpret_cast<uint2*>(out)[i] = *reinterpret_cast<uint2*>(o);
}

// ------------- tiled transpose fp32 (K,N) -> bf16 (Npad,K), zero-pad n>=N -------------
__global__ __launch_bounds__(256) void wtrans(const float* __restrict__ in,
                                              BF* __restrict__ out,
                                              int K, int N, int Npad) {
  __shared__ float t[32][33];
  int n0 = blockIdx.x * 32, k0 = blockIdx.y * 32;
  int tx = threadIdx.x, ty = threadIdx.y;
#pragma unroll
  for (int j = 0; j < 4; j++) {
    int k = k0 + ty + j * 8, n = n0 + tx;
    t[ty + j * 8][tx] = (n < N) ? in[(size_t)k * N + n] : 0.f;
  }
  __syncthreads();
#pragma unroll
  for (int j = 0; j < 4; j++) {
    int n = n0 + ty + j * 8, k = k0 + tx;
    out[(size_t)n * K + k] = __float2bfloat16(t[tx][ty + j * 8]);
  }
}

// ---------------- GEMM: C = A(M,K) x Bt(N,K)^T, bf16 in, fp32 acc ----------------
// 128x128 tile, BK=32, 256 threads = 4 waves (2x2), each wave 64x64 (4x4 frags).
template <int MODE>
__global__ __launch_bounds__(256) void gemm_bt(const BF* __restrict__ A,
                                               const BF* __restrict__ Bt,
                                               void* __restrict__ C,
                                               int M, int N, int K) {
  __shared__ BF As[128][32];
  __shared__ BF Bs[128][32];
  const int tid = threadIdx.x;
  const int w = tid >> 6, l = tid & 63;
  const int lr = l & 15, lg = l >> 4;
  const int wr = w >> 1, wc = w & 1;
  const int m0 = blockIdx.y * 128, n0 = blockIdx.x * 128;

  f32x4 acc[4][4];
#pragma unroll
  for (int m = 0; m < 4; m++)
#pragma unroll
    for (int n = 0; n < 4; n++) acc[m][n] = (f32x4){0.f, 0.f, 0.f, 0.f};

  for (int k0 = 0; k0 < K; k0 += 32) {
    __syncthreads();
#pragma unroll
    for (int j = 0; j < 2; j++) {
      int idx = tid + j * 256;
      int row = idx >> 2, seg = idx & 3;
      *reinterpret_cast<bf16x8*>(&As[row][seg * 8]) =
          *reinterpret_cast<const bf16x8*>(A + (size_t)(m0 + row) * K + k0 + seg * 8);
      *reinterpret_cast<bf16x8*>(&Bs[row][seg * 8]) =
          *reinterpret_cast<const bf16x8*>(Bt + (size_t)(n0 + row) * K + k0 + seg * 8);
    }
    __syncthreads();
    bf16x8 af[4], bfr[4];
#pragma unroll
    for (int m = 0; m < 4; m++)
      af[m] = *reinterpret_cast<const bf16x8*>(&As[wr * 64 + m * 16 + lr][lg * 8]);
#pragma unroll
    for (int n = 0; n < 4; n++)
      bfr[n] = *reinterpret_cast<const bf16x8*>(&Bs[wc * 64 + n * 16 + lr][lg * 8]);
#pragma unroll
    for (int m = 0; m < 4; m++)
#pragma unroll
      for (int n = 0; n < 4; n++) acc[m][n] = mfma16(af[m], bfr[n], acc[m][n]);
  }

  // epilogue: C/D layout col = lane&15, row = (lane>>4)*4 + j  (m89-verified)
#pragma unroll
  for (int m = 0; m < 4; m++) {
#pragma unroll
    for (int n = 0; n < 4; n++) {
#pragma unroll
      for (int j = 0; j < 4; j++) {
        int row = m0 + wr * 64 + m * 16 + lg * 4 + j;
        int col = n0 + wc * 64 + n * 16 + lr;
        float v = acc[m][n][j];
        if constexpr (MODE == 0) {
          ((BF*)C)[(size_t)row * N + col] = __float2bfloat16(v);
        } else if constexpr (MODE == 1) {
          int b = row >> 11, s = row & 2047, h = col >> 7, d = col & 127;
          ((BF*)C)[((size_t)(b * 16 + h) * 2048 + s) * 192 + d] = __float2bfloat16(v);
        } else if constexpr (MODE == 2) {
          int b = row >> 11, s = row & 2047, h = col >> 7, d = col & 127;
          ((BF*)C)[((size_t)(b * 16 + h) * 128 + d) * 2048 + s] = __float2bfloat16(v);
        } else {
          ((float*)C)[(size_t)row * N + col] = v;
        }
      }
    }
  }
}

// ---------------- RoPE ----------------
__global__ __launch_bounds__(256) void rope_q(const BF* __restrict__ qr, BF* __restrict__ qb) {
  int idx = blockIdx.x * 256 + threadIdx.x;  // 4096*16*64
  int d = idx & 63, h = (idx >> 6) & 15, m = idx >> 10;
  int s = m & 2047, b = m >> 11;
  float x = __bfloat162float(qr[(size_t)(m << 10) + (h << 6) + d]);
  float other = __bfloat162float(qr[(size_t)(m << 10) + (h << 6) + (d ^ 32)]);
  float rot = (d < 32) ? -other : other;
  int di = d & 31;
  float arg = (float)s * powf(10000.f, -(float)di / 32.0f);
  float c = cosf(arg), sn = sinf(arg);
  qb[((size_t)(b * 16 + h) * 2048 + s) * 192 + 128 + d] = __float2bfloat16(x * c + rot * sn);
}

__global__ __launch_bounds__(256) void rope_k(const BF* __restrict__ kr, BF* __restrict__ kb) {
  int idx = blockIdx.x * 256 + threadIdx.x;  // 4096*64
  int d = idx & 63, m = idx >> 6;
  int s = m & 2047, b = m >> 11;
  float x = __bfloat162float(kr[(size_t)m * 128 + d]);
  float other = __bfloat162float(kr[(size_t)m * 128 + (d ^ 32)]);
  float rot = (d < 32) ? -other : other;
  int di = d & 31;
  float arg = (float)s * powf(10000.f, -(float)di / 32.0f);
  float val = x * cosf(arg) + rot * sinf(arg);
  BF v = __float2bfloat16(val);
#pragma unroll
  for (int h = 0; h < 16; h++)
    kb[((size_t)(b * 16 + h) * 2048 + s) * 192 + 128 + d] = v;
}

// ---------------- flash attention v2 ----------------
// QBLK=128, KVBLK=64. grid (S/128, B*NH), 256 thr = 4 waves.
// Wave w owns q-rows [q0 + w*32, +32) as 2 row-frags of 16.
// Per chunk per wave: 48 QK-MFMA + 32 PV-MFMA across 3 barriers.
__global__ __launch_bounds__(256) void attn_kern(const BF* __restrict__ qb,
                                                 const BF* __restrict__ kb,
                                                 const BF* __restrict__ vT,
                                                 BF* __restrict__ o) {
  const int bh = blockIdx.y;
  const int q0 = ((int)gridDim.x - 1 - (int)blockIdx.x) * 128;  // longest blocks first
  const int tid = threadIdx.x;
  const int w = tid >> 6, l = tid & 63;
  const int lr = l & 15, lg = l >> 4;

  __shared__ BF Ks[64][200];       // 64 keys x 192 (pad 200)      25.6 KB
  __shared__ BF Vs[128][72];       // 128 dims x 64 keys (pad 72)  18.4 KB
  __shared__ BF Ps[4][32][72];     // per-wave P: 32 rows x 64     18.4 KB

  // Q fragments hoisted: 2 row-frags x 6 K-chunks
  bf16x8 aq[2][6];
#pragma unroll
  for (int rf = 0; rf < 2; rf++) {
    const BF* qrow = qb + ((size_t)bh * 2048 + q0 + w * 32 + rf * 16 + lr) * 192;
#pragma unroll
    for (int kk = 0; kk < 6; kk++)
      aq[rf][kk] = *reinterpret_cast<const bf16x8*>(qrow + kk * 32 + lg * 8);
  }

  f32x4 Oacc[2][8];
#pragma unroll
  for (int rf = 0; rf < 2; rf++)
#pragma unroll
    for (int d = 0; d < 8; d++) Oacc[rf][d] = (f32x4){0.f, 0.f, 0.f, 0.f};
  float mrow[2][4], lrow[2][4];
#pragma unroll
  for (int rf = 0; rf < 2; rf++)
#pragma unroll
    for (int j = 0; j < 4; j++) { mrow[rf][j] = -3e38f; lrow[rf][j] = 0.f; }

  const float scale = 0.07216878364870323f;  // 1/sqrt(192)
  const int nch = (q0 + 128) >> 6;

  for (int ch = 0; ch < nch; ch++) {
    const int c0 = ch << 6;
    __syncthreads();
    // stage K tile (64x192): 1536 v8-loads / 256 thr = 6 each
#pragma unroll
    for (int j2 = 0; j2 < 6; j2++) {
      int idx = tid + j2 * 256;
      int row = idx / 24, seg = idx % 24;
      *reinterpret_cast<bf16x8*>(&Ks[row][seg * 8]) =
          *reinterpret_cast<const bf16x8*>(kb + ((size_t)bh * 2048 + c0 + row) * 192 + seg * 8);
    }
    // stage V^T tile (128x64): 1024 v8-loads / 256 thr = 4 each
#pragma unroll
    for (int j2 = 0; j2 < 4; j2++) {
      int idx = tid + j2 * 256;
      int row = idx >> 3, seg = idx & 7;
      *reinterpret_cast<bf16x8*>(&Vs[row][seg * 8]) =
          *reinterpret_cast<const bf16x8*>(vT + ((size_t)bh * 128 + row) * 2048 + c0 + seg * 8);
    }
    __syncthreads();

#pragma unroll
    for (int rf = 0; rf < 2; rf++) {
      // QK^T: 16 rows x 64 cols as four 16x16 frags
      f32x4 sf[4];
#pragma unroll
      for (int cf = 0; cf < 4; cf++) {
        sf[cf] = (f32x4){0.f, 0.f, 0.f, 0.f};
#pragma unroll
        for (int kk = 0; kk < 6; kk++) {
          bf16x8 bfr = *reinterpret_cast<const bf16x8*>(&Ks[cf * 16 + lr][kk * 32 + lg * 8]);
          sf[cf] = mfma16(aq[rf][kk], bfr, sf[cf]);
        }
      }
      // scale + causal mask
      const int rbase = q0 + w * 32 + rf * 16 + lg * 4;
#pragma unroll
      for (int cf = 0; cf < 4; cf++) {
        int cg = c0 + cf * 16 + lr;
#pragma unroll
        for (int j = 0; j < 4; j++) {
          float s = sf[cf][j] * scale;
          sf[cf][j] = (cg <= rbase + j) ? s : -1e30f;
        }
      }
      // online softmax: per j, reduce over 4 in-lane frags + 16 lanes (lr)
#pragma unroll
      for (int j = 0; j < 4; j++) {
        float mx = fmaxf(fmaxf(sf[0][j], sf[1][j]), fmaxf(sf[2][j], sf[3][j]));
#pragma unroll
        for (int t = 1; t < 16; t <<= 1) mx = fmaxf(mx, __shfl_xor(mx, t, 64));
        float mnew = fmaxf(mrow[rf][j], mx);
        float corr = __expf(mrow[rf][j] - mnew);
        float p0 = __expf(sf[0][j] - mnew);
        float p1 = __expf(sf[1][j] - mnew);
        float p2 = __expf(sf[2][j] - mnew);
        float p3 = __expf(sf[3][j] - mnew);
        float sum = (p0 + p1) + (p2 + p3);
#pragma unroll
        for (int t = 1; t < 16; t <<= 1) sum += __shfl_xor(sum, t, 64);
        lrow[rf][j] = lrow[rf][j] * corr + sum;
        mrow[rf][j] = mnew;
#pragma unroll
        for (int d = 0; d < 8; d++) Oacc[rf][d][j] *= corr;
        int prow = rf * 16 + lg * 4 + j;
        Ps[w][prow][lr]      = __float2bfloat16(p0);
        Ps[w][prow][16 + lr] = __float2bfloat16(p1);
        Ps[w][prow][32 + lr] = __float2bfloat16(p2);
        Ps[w][prow][48 + lr] = __float2bfloat16(p3);
      }
    }
    __syncthreads();  // P visible (also keeps chunk phases aligned across waves)

    // PV: O[q][d] += P(32x64) x V^T(d,k); V-frags shared across both row-frags
    bf16x8 pf[2][2];
#pragma unroll
    for (int rf = 0; rf < 2; rf++)
#pragma unroll
      for (int ks = 0; ks < 2; ks++)
        pf[rf][ks] = *reinterpret_cast<const bf16x8*>(&Ps[w][rf * 16 + lr][ks * 32 + lg * 8]);
#pragma unroll
    for (int ks = 0; ks < 2; ks++) {
#pragma unroll
      for (int d = 0; d < 8; d++) {
        bf16x8 vf = *reinterpret_cast<const bf16x8*>(&Vs[d * 16 + lr][ks * 32 + lg * 8]);
        Oacc[0][d] = mfma16(pf[0][ks], vf, Oacc[0][d]);
        Oacc[1][d] = mfma16(pf[1][ks], vf, Oacc[1][d]);
      }
    }
  }

  // epilogue
  const int b = bh >> 4, h = bh & 15;
#pragma unroll
  for (int rf = 0; rf < 2; rf++) {
#pragma unroll
    for (int j = 0; j < 4; j++) {
      float rinv = 1.0f / lrow[rf][j];
      int srow = q0 + w * 32 + rf * 16 + lg * 4 + j;
#pragma unroll
      for (int d = 0; d < 8; d++) {
        o[((size_t)(b * 2048 + srow)) * 2048 + h * 128 + d * 16 + lr] =
            __float2bfloat16(Oacc[rf][d][j] * rinv);
      }
    }
  }
}

extern "C" void kernel_launch(void* const* d_in, const int* in_sizes, int n_in,
                              void* d_out, int out_size, void* d_ws, size_t ws_size,
                              hipStream_t stream) {
  const float* hs   = (const float*)d_in[0];
  const float* wDKV = (const float*)d_in[2];
  const float* wUK  = (const float*)d_in[3];
  const float* wUV  = (const float*)d_in[4];
  const float* wDQ  = (const float*)d_in[5];
  const float* wUQ  = (const float*)d_in[6];
  const float* wQR  = (const float*)d_in[7];
  const float* wKR  = (const float*)d_in[8];
  const float* wO   = (const float*)d_in[9];
  float* out = (float*)d_out;

  char* ws = (char*)d_ws;
  size_t off = 0;
  auto alloc = [&](size_t bytes) -> char* {
    char* p = ws + off;
    off += (bytes + 255) & ~(size_t)255;
    return p;
  };
  BF* hsb   = (BF*)alloc((size_t)M_ * HID_ * 2);        // 4096x2048
  BF* tDKV  = (BF*)alloc((size_t)CKV_ * HID_ * 2);      // (512,2048)
  BF* tUK   = (BF*)alloc((size_t)(NH_*HD_) * CKV_ * 2); // (2048,512)
  BF* tUV   = (BF*)alloc((size_t)(NH_*HD_) * CKV_ * 2); // (2048,512)
  BF* tDQ   = (BF*)alloc((size_t)CQ_ * HID_ * 2);       // (1024,2048)
  BF* tUQ   = (BF*)alloc((size_t)(NH_*HD_) * CQ_ * 2);  // (2048,1024)
  BF* tQR   = (BF*)alloc((size_t)(NH_*RD_) * CQ_ * 2);  // (1024,1024)
  BF* tKR   = (BF*)alloc((size_t)128 * HID_ * 2);       // (128,2048) padded
  BF* tWO   = (BF*)alloc((size_t)HID_ * (NH_*HD_) * 2); // (2048,2048)
  BF* cKV   = (BF*)alloc((size_t)M_ * CKV_ * 2);
  BF* cQ    = (BF*)alloc((size_t)M_ * CQ_ * 2);
  BF* qbuf  = (BF*)alloc((size_t)B_ * NH_ * S_ * DQK_ * 2);
  BF* kbuf  = (BF*)alloc((size_t)B_ * NH_ * S_ * DQK_ * 2);
  BF* vTb   = (BF*)alloc((size_t)B_ * NH_ * HD_ * S_ * 2);
  BF* qRt   = (BF*)alloc((size_t)M_ * (NH_*RD_) * 2);
  BF* kRt   = (BF*)alloc((size_t)M_ * 128 * 2);
  BF* aout  = (BF*)alloc((size_t)M_ * (NH_*HD_) * 2);

  // 1. hidden -> bf16
  f2b_kern<<<(M_ * HID_ / 4 + 255) / 256, 256, 0, stream>>>(hs, hsb, M_ * HID_ / 4);

  // 2. weight transposes (fp32 (K,N) -> bf16 (Npad,K))
  dim3 tb(32, 8);
  wtrans<<<dim3(CKV_ / 32, HID_ / 32), tb, 0, stream>>>(wDKV, tDKV, HID_, CKV_, CKV_);
  wtrans<<<dim3((NH_*HD_) / 32, CKV_ / 32), tb, 0, stream>>>(wUK, tUK, CKV_, NH_*HD_, NH_*HD_);
  wtrans<<<dim3((NH_*HD_) / 32, CKV_ / 32), tb, 0, stream>>>(wUV, tUV, CKV_, NH_*HD_, NH_*HD_);
  wtrans<<<dim3(CQ_ / 32, HID_ / 32), tb, 0, stream>>>(wDQ, tDQ, HID_, CQ_, CQ_);
  wtrans<<<dim3((NH_*HD_) / 32, CQ_ / 32), tb, 0, stream>>>(wUQ, tUQ, CQ_, NH_*HD_, NH_*HD_);
  wtrans<<<dim3((NH_*RD_) / 32, CQ_ / 32), tb, 0, stream>>>(wQR, tQR, CQ_, NH_*RD_, NH_*RD_);
  wtrans<<<dim3(128 / 32, HID_ / 32), tb, 0, stream>>>(wKR, tKR, HID_, RD_, 128);
  wtrans<<<dim3((NH_*HD_) / 32, HID_ / 32), tb, 0, stream>>>(wO, tWO, HID_, NH_*HD_, NH_*HD_);

  // 3. projections
  gemm_bt<0><<<dim3(CKV_ / 128, M_ / 128), 256, 0, stream>>>(hsb, tDKV, cKV, M_, CKV_, HID_);
  gemm_bt<0><<<dim3(CQ_ / 128, M_ / 128), 256, 0, stream>>>(hsb, tDQ, cQ, M_, CQ_, HID_);
  gemm_bt<1><<<dim3((NH_*HD_) / 128, M_ / 128), 256, 0, stream>>>(cKV, tUK, kbuf, M_, NH_*HD_, CKV_);
  gemm_bt<2><<<dim3((NH_*HD_) / 128, M_ / 128), 256, 0, stream>>>(cKV, tUV, vTb, M_, NH_*HD_, CKV_);
  gemm_bt<1><<<dim3((NH_*HD_) / 128, M_ / 128), 256, 0, stream>>>(cQ, tUQ, qbuf, M_, NH_*HD_, CQ_);
  gemm_bt<0><<<dim3((NH_*RD_) / 128, M_ / 128), 256, 0, stream>>>(cQ, tQR, qRt, M_, NH_*RD_, CQ_);
  gemm_bt<0><<<dim3(128 / 128, M_ / 128), 256, 0, stream>>>(hsb, tKR, kRt, M_, 128, HID_);

  // 4. RoPE
  rope_q<<<(M_ * NH_ * RD_) / 256, 256, 0, stream>>>(qRt, qbuf);
  rope_k<<<(M_ * RD_) / 256, 256, 0, stream>>>(kRt, kbuf);

  // 5. attention (QBLK=128, KVBLK=64)
  attn_kern<<<dim3(S_ / 128, B_ * NH_), 256, 0, stream>>>(qbuf, kbuf, vTb, aout);

  // 6. output projection (fp32 out)
  gemm_bt<3><<<dim3((NH_*HD_) / 128, M_ / 128), 256, 0, stream>>>(aout, tWO, out, M_, NH_*HD_, HID_);
}

// Round 5
// 551.878 us; speedup vs baseline: 1.1006x; 1.0739x over previous
//
#include <hip/hip_runtime.h>
#include <hip/hip_bf16.h>

typedef __bf16 bf16x8 __attribute__((ext_vector_type(8)));
typedef float f32x4 __attribute__((ext_vector_type(4)));
using BF = __hip_bfloat16;

// Problem constants
constexpr int B_   = 2;
constexpr int S_   = 2048;
constexpr int NH_  = 16;
constexpr int HD_  = 128;
constexpr int HID_ = 2048;
constexpr int CKV_ = 512;
constexpr int CQ_  = 1024;
constexpr int RD_  = 64;
constexpr int M_   = B_ * S_;     // 4096 tokens
constexpr int DQK_ = HD_ + RD_;   // 192

__device__ __forceinline__ f32x4 mfma16(bf16x8 a, bf16x8 b, f32x4 c) {
  return __builtin_amdgcn_mfma_f32_16x16x32_bf16(a, b, c, 0, 0, 0);
}

// ---------------- fp32 -> bf16 convert (vectorized) ----------------
__global__ __launch_bounds__(256) void f2b_kern(const float* __restrict__ in,
                                                BF* __restrict__ out, int n4) {
  int i = blockIdx.x * 256 + threadIdx.x;
  if (i >= n4) return;
  float4 v = reinterpret_cast<const float4*>(in)[i];
  BF o[4] = {__float2bfloat16(v.x), __float2bfloat16(v.y),
             __float2bfloat16(v.z), __float2bfloat16(v.w)};
  reinterpret_cast<uint2*>(out)[i] = *reinterpret_cast<uint2*>(o);
}

// ------------- tiled transpose fp32 (K,N) -> bf16 (Npad,K), zero-pad n>=N -------------
__global__ __launch_bounds__(256) void wtrans(const float* __restrict__ in,
                                              BF* __restrict__ out,
                                              int K, int N, int Npad) {
  __shared__ float t[32][33];
  int n0 = blockIdx.x * 32, k0 = blockIdx.y * 32;
  int tx = threadIdx.x, ty = threadIdx.y;
#pragma unroll
  for (int j = 0; j < 4; j++) {
    int k = k0 + ty + j * 8, n = n0 + tx;
    t[ty + j * 8][tx] = (n < N) ? in[(size_t)k * N + n] : 0.f;
  }
  __syncthreads();
#pragma unroll
  for (int j = 0; j < 4; j++) {
    int n = n0 + ty + j * 8, k = k0 + tx;
    out[(size_t)n * K + k] = __float2bfloat16(t[tx][ty + j * 8]);
  }
}

// ---------------- GEMM: C = A(M,K) x Bt(N,K)^T, bf16 in, fp32 acc ----------------
// 128x128 tile, BK=32, 256 threads = 4 waves (2x2), each wave 64x64 (4x4 frags).
template <int MODE>
__global__ __launch_bounds__(256) void gemm_bt(const BF* __restrict__ A,
                                               const BF* __restrict__ Bt,
                                               void* __restrict__ C,
                                               int M, int N, int K) {
  __shared__ BF As[128][32];
  __shared__ BF Bs[128][32];
  const int tid = threadIdx.x;
  const int w = tid >> 6, l = tid & 63;
  const int lr = l & 15, lg = l >> 4;
  const int wr = w >> 1, wc = w & 1;
  const int m0 = blockIdx.y * 128, n0 = blockIdx.x * 128;

  f32x4 acc[4][4];
#pragma unroll
  for (int m = 0; m < 4; m++)
#pragma unroll
    for (int n = 0; n < 4; n++) acc[m][n] = (f32x4){0.f, 0.f, 0.f, 0.f};

  for (int k0 = 0; k0 < K; k0 += 32) {
    __syncthreads();
#pragma unroll
    for (int j = 0; j < 2; j++) {
      int idx = tid + j * 256;
      int row = idx >> 2, seg = idx & 3;
      *reinterpret_cast<bf16x8*>(&As[row][seg * 8]) =
          *reinterpret_cast<const bf16x8*>(A + (size_t)(m0 + row) * K + k0 + seg * 8);
      *reinterpret_cast<bf16x8*>(&Bs[row][seg * 8]) =
          *reinterpret_cast<const bf16x8*>(Bt + (size_t)(n0 + row) * K + k0 + seg * 8);
    }
    __syncthreads();
    bf16x8 af[4], bfr[4];
#pragma unroll
    for (int m = 0; m < 4; m++)
      af[m] = *reinterpret_cast<const bf16x8*>(&As[wr * 64 + m * 16 + lr][lg * 8]);
#pragma unroll
    for (int n = 0; n < 4; n++)
      bfr[n] = *reinterpret_cast<const bf16x8*>(&Bs[wc * 64 + n * 16 + lr][lg * 8]);
#pragma unroll
    for (int m = 0; m < 4; m++)
#pragma unroll
      for (int n = 0; n < 4; n++) acc[m][n] = mfma16(af[m], bfr[n], acc[m][n]);
  }

  // epilogue: C/D layout col = lane&15, row = (lane>>4)*4 + j  (m89-verified)
#pragma unroll
  for (int m = 0; m < 4; m++) {
#pragma unroll
    for (int n = 0; n < 4; n++) {
#pragma unroll
      for (int j = 0; j < 4; j++) {
        int row = m0 + wr * 64 + m * 16 + lg * 4 + j;
        int col = n0 + wc * 64 + n * 16 + lr;
        float v = acc[m][n][j];
        if constexpr (MODE == 0) {
          ((BF*)C)[(size_t)row * N + col] = __float2bfloat16(v);
        } else if constexpr (MODE == 1) {
          int b = row >> 11, s = row & 2047, h = col >> 7, d = col & 127;
          ((BF*)C)[((size_t)(b * 16 + h) * 2048 + s) * 192 + d] = __float2bfloat16(v);
        } else if constexpr (MODE == 2) {
          int b = row >> 11, s = row & 2047, h = col >> 7, d = col & 127;
          ((BF*)C)[((size_t)(b * 16 + h) * 128 + d) * 2048 + s] = __float2bfloat16(v);
        } else {
          ((float*)C)[(size_t)row * N + col] = v;
        }
      }
    }
  }
}

// ---------------- RoPE ----------------
__global__ __launch_bounds__(256) void rope_q(const BF* __restrict__ qr, BF* __restrict__ qb) {
  int idx = blockIdx.x * 256 + threadIdx.x;  // 4096*16*64
  int d = idx & 63, h = (idx >> 6) & 15, m = idx >> 10;
  int s = m & 2047, b = m >> 11;
  float x = __bfloat162float(qr[(size_t)(m << 10) + (h << 6) + d]);
  float other = __bfloat162float(qr[(size_t)(m << 10) + (h << 6) + (d ^ 32)]);
  float rot = (d < 32) ? -other : other;
  int di = d & 31;
  float arg = (float)s * powf(10000.f, -(float)di / 32.0f);
  float c = cosf(arg), sn = sinf(arg);
  qb[((size_t)(b * 16 + h) * 2048 + s) * 192 + 128 + d] = __float2bfloat16(x * c + rot * sn);
}

__global__ __launch_bounds__(256) void rope_k(const BF* __restrict__ kr, BF* __restrict__ kb) {
  int idx = blockIdx.x * 256 + threadIdx.x;  // 4096*64
  int d = idx & 63, m = idx >> 6;
  int s = m & 2047, b = m >> 11;
  float x = __bfloat162float(kr[(size_t)m * 128 + d]);
  float other = __bfloat162float(kr[(size_t)m * 128 + (d ^ 32)]);
  float rot = (d < 32) ? -other : other;
  int di = d & 31;
  float arg = (float)s * powf(10000.f, -(float)di / 32.0f);
  float val = x * cosf(arg) + rot * sinf(arg);
  BF v = __float2bfloat16(val);
#pragma unroll
  for (int h = 0; h < 16; h++)
    kb[((size_t)(b * 16 + h) * 2048 + s) * 192 + 128 + d] = v;
}

// ---------------- flash attention v3: swapped QK^T, in-lane softmax ----------------
// QBLK=128, KVBLK=64. grid (S/128, B*NH), 256 thr = 4 waves, wave owns 32 q-rows.
// S^T = mfma(K,Q): lane (lr,lg) holds S[key=kf*16+lg*4+j][q=lr] -> row-softmax is
// 15 in-lane ops + 2 shuffles (vs 64 shuffle-chain ops in v2).
__global__ __launch_bounds__(256) void attn_kern(const BF* __restrict__ qb,
                                                 const BF* __restrict__ kb,
                                                 const BF* __restrict__ vT,
                                                 BF* __restrict__ o) {
  const int bh = blockIdx.y;
  const int q0 = ((int)gridDim.x - 1 - (int)blockIdx.x) * 128;  // longest blocks first
  const int tid = threadIdx.x;
  const int w = tid >> 6, l = tid & 63;
  const int lr = l & 15, lg = l >> 4;

  __shared__ BF Ks[64][200];       // 64 keys x 192 (pad 200)
  __shared__ BF Vs[128][72];       // 128 dims x 64 keys (pad 72)
  __shared__ BF Ps[4][32][72];     // per-wave P: 32 q-rows x 64 keys
  __shared__ float corrS[4][2][16];
  __shared__ float lS[4][2][16];

  // Q fragments (used as MFMA B-operand): 2 row-frags x 6 K-chunks
  bf16x8 aq[2][6];
#pragma unroll
  for (int rf = 0; rf < 2; rf++) {
    const BF* qrow = qb + ((size_t)bh * 2048 + q0 + w * 32 + rf * 16 + lr) * 192;
#pragma unroll
    for (int kk = 0; kk < 6; kk++)
      aq[rf][kk] = *reinterpret_cast<const bf16x8*>(qrow + kk * 32 + lg * 8);
  }

  f32x4 Oacc[2][8];
#pragma unroll
  for (int rf = 0; rf < 2; rf++)
#pragma unroll
    for (int d = 0; d < 8; d++) Oacc[rf][d] = (f32x4){0.f, 0.f, 0.f, 0.f};
  // softmax stats for q = lr (kept redundantly in 4 lg-lanes), per row-frag
  float mrow[2] = {-3e38f, -3e38f}, lrow[2] = {0.f, 0.f};

  const float scale = 0.07216878364870323f;  // 1/sqrt(192)
  const int nch = (q0 + 128) >> 6;

  for (int ch = 0; ch < nch; ch++) {
    const int c0 = ch << 6;
    __syncthreads();
    // stage K tile (64x192)
#pragma unroll
    for (int j2 = 0; j2 < 6; j2++) {
      int idx = tid + j2 * 256;
      int row = idx / 24, seg = idx % 24;
      *reinterpret_cast<bf16x8*>(&Ks[row][seg * 8]) =
          *reinterpret_cast<const bf16x8*>(kb + ((size_t)bh * 2048 + c0 + row) * 192 + seg * 8);
    }
    // stage V^T tile (128x64)
#pragma unroll
    for (int j2 = 0; j2 < 4; j2++) {
      int idx = tid + j2 * 256;
      int row = idx >> 3, seg = idx & 7;
      *reinterpret_cast<bf16x8*>(&Vs[row][seg * 8]) =
          *reinterpret_cast<const bf16x8*>(vT + ((size_t)bh * 128 + row) * 2048 + c0 + seg * 8);
    }
    __syncthreads();

#pragma unroll
    for (int rf = 0; rf < 2; rf++) {
      // S^T = K x Q^T: 4 key-frags of 16, all for q = lr
      f32x4 sf[4];
#pragma unroll
      for (int kf = 0; kf < 4; kf++) {
        sf[kf] = (f32x4){0.f, 0.f, 0.f, 0.f};
#pragma unroll
        for (int kk = 0; kk < 6; kk++) {
          bf16x8 kfr = *reinterpret_cast<const bf16x8*>(&Ks[kf * 16 + lr][kk * 32 + lg * 8]);
          sf[kf] = mfma16(kfr, aq[rf][kk], sf[kf]);
        }
      }
      // scale + causal mask: key = c0+kf*16+lg*4+j, q = q0+w*32+rf*16+lr
      const int rq = q0 + w * 32 + rf * 16 + lr;
#pragma unroll
      for (int kf = 0; kf < 4; kf++) {
        int kgb = c0 + kf * 16 + lg * 4;
#pragma unroll
        for (int j = 0; j < 4; j++)
          sf[kf][j] = (kgb + j <= rq) ? sf[kf][j] * scale : -1e30f;
      }
      // in-lane max over 16, then combine the 4 lg-copies (2 shuffles)
      float mx = -3e38f;
#pragma unroll
      for (int kf = 0; kf < 4; kf++)
        mx = fmaxf(fmaxf(fmaxf(mx, sf[kf][0]), fmaxf(sf[kf][1], sf[kf][2])), sf[kf][3]);
      mx = fmaxf(mx, __shfl_xor(mx, 16, 64));
      mx = fmaxf(mx, __shfl_xor(mx, 32, 64));
      float mnew = fmaxf(mrow[rf], mx);
      float corr = __expf(mrow[rf] - mnew);
      // p = exp(s - mnew); in-lane sum + 2 shuffles; pack 4 bf16 -> one 8B write
      float psum = 0.f;
#pragma unroll
      for (int kf = 0; kf < 4; kf++) {
        BF p4[4];
#pragma unroll
        for (int j = 0; j < 4; j++) {
          float p = __expf(sf[kf][j] - mnew);
          psum += p;
          p4[j] = __float2bfloat16(p);
        }
        *reinterpret_cast<uint2*>(&Ps[w][rf * 16 + lr][kf * 16 + lg * 4]) =
            *reinterpret_cast<uint2*>(p4);
      }
      psum += __shfl_xor(psum, 16, 64);
      psum += __shfl_xor(psum, 32, 64);
      lrow[rf] = lrow[rf] * corr + psum;
      mrow[rf] = mnew;
      if (lg == 0) corrS[w][rf][lr] = corr;
    }
    __syncthreads();  // P + corr visible; Ks/Vs safe to reuse next iter

    // redistribute corr to PV-accumulator layout (q = lg*4+j) and rescale O
#pragma unroll
    for (int rf = 0; rf < 2; rf++) {
      float c4[4];
#pragma unroll
      for (int j = 0; j < 4; j++) c4[j] = corrS[w][rf][lg * 4 + j];
#pragma unroll
      for (int d = 0; d < 8; d++)
#pragma unroll
        for (int j = 0; j < 4; j++) Oacc[rf][d][j] *= c4[j];
    }

    // PV: O[q][d] += P(32x64) x V^T; V-frags shared across both row-frags
    bf16x8 pf[2][2];
#pragma unroll
    for (int rf = 0; rf < 2; rf++)
#pragma unroll
      for (int ks = 0; ks < 2; ks++)
        pf[rf][ks] = *reinterpret_cast<const bf16x8*>(&Ps[w][rf * 16 + lr][ks * 32 + lg * 8]);
#pragma unroll
    for (int ks = 0; ks < 2; ks++) {
#pragma unroll
      for (int d = 0; d < 8; d++) {
        bf16x8 vf = *reinterpret_cast<const bf16x8*>(&Vs[d * 16 + lr][ks * 32 + lg * 8]);
        Oacc[0][d] = mfma16(pf[0][ks], vf, Oacc[0][d]);
        Oacc[1][d] = mfma16(pf[1][ks], vf, Oacc[1][d]);
      }
    }
  }

  // epilogue: redistribute l to (lg,j) layout, then store
  if (lg == 0) {
    lS[w][0][lr] = lrow[0];
    lS[w][1][lr] = lrow[1];
  }
  __syncthreads();
  const int b = bh >> 4, h = bh & 15;
#pragma unroll
  for (int rf = 0; rf < 2; rf++) {
#pragma unroll
    for (int j = 0; j < 4; j++) {
      float rinv = 1.0f / lS[w][rf][lg * 4 + j];
      int srow = q0 + w * 32 + rf * 16 + lg * 4 + j;
#pragma unroll
      for (int d = 0; d < 8; d++) {
        o[((size_t)(b * 2048 + srow)) * 2048 + h * 128 + d * 16 + lr] =
            __float2bfloat16(Oacc[rf][d][j] * rinv);
      }
    }
  }
}

extern "C" void kernel_launch(void* const* d_in, const int* in_sizes, int n_in,
                              void* d_out, int out_size, void* d_ws, size_t ws_size,
                              hipStream_t stream) {
  const float* hs   = (const float*)d_in[0];
  const float* wDKV = (const float*)d_in[2];
  const float* wUK  = (const float*)d_in[3];
  const float* wUV  = (const float*)d_in[4];
  const float* wDQ  = (const float*)d_in[5];
  const float* wUQ  = (const float*)d_in[6];
  const float* wQR  = (const float*)d_in[7];
  const float* wKR  = (const float*)d_in[8];
  const float* wO   = (const float*)d_in[9];
  float* out = (float*)d_out;

  char* ws = (char*)d_ws;
  size_t off = 0;
  auto alloc = [&](size_t bytes) -> char* {
    char* p = ws + off;
    off += (bytes + 255) & ~(size_t)255;
    return p;
  };
  BF* hsb   = (BF*)alloc((size_t)M_ * HID_ * 2);        // 4096x2048
  BF* tDKV  = (BF*)alloc((size_t)CKV_ * HID_ * 2);      // (512,2048)
  BF* tUK   = (BF*)alloc((size_t)(NH_*HD_) * CKV_ * 2); // (2048,512)
  BF* tUV   = (BF*)alloc((size_t)(NH_*HD_) * CKV_ * 2); // (2048,512)
  BF* tDQ   = (BF*)alloc((size_t)CQ_ * HID_ * 2);       // (1024,2048)
  BF* tUQ   = (BF*)alloc((size_t)(NH_*HD_) * CQ_ * 2);  // (2048,1024)
  BF* tQR   = (BF*)alloc((size_t)(NH_*RD_) * CQ_ * 2);  // (1024,1024)
  BF* tKR   = (BF*)alloc((size_t)128 * HID_ * 2);       // (128,2048) padded
  BF* tWO   = (BF*)alloc((size_t)HID_ * (NH_*HD_) * 2); // (2048,2048)
  BF* cKV   = (BF*)alloc((size_t)M_ * CKV_ * 2);
  BF* cQ    = (BF*)alloc((size_t)M_ * CQ_ * 2);
  BF* qbuf  = (BF*)alloc((size_t)B_ * NH_ * S_ * DQK_ * 2);
  BF* kbuf  = (BF*)alloc((size_t)B_ * NH_ * S_ * DQK_ * 2);
  BF* vTb   = (BF*)alloc((size_t)B_ * NH_ * HD_ * S_ * 2);
  BF* qRt   = (BF*)alloc((size_t)M_ * (NH_*RD_) * 2);
  BF* kRt   = (BF*)alloc((size_t)M_ * 128 * 2);
  BF* aout  = (BF*)alloc((size_t)M_ * (NH_*HD_) * 2);

  // 1. hidden -> bf16
  f2b_kern<<<(M_ * HID_ / 4 + 255) / 256, 256, 0, stream>>>(hs, hsb, M_ * HID_ / 4);

  // 2. weight transposes (fp32 (K,N) -> bf16 (Npad,K))
  dim3 tb(32, 8);
  wtrans<<<dim3(CKV_ / 32, HID_ / 32), tb, 0, stream>>>(wDKV, tDKV, HID_, CKV_, CKV_);
  wtrans<<<dim3((NH_*HD_) / 32, CKV_ / 32), tb, 0, stream>>>(wUK, tUK, CKV_, NH_*HD_, NH_*HD_);
  wtrans<<<dim3((NH_*HD_) / 32, CKV_ / 32), tb, 0, stream>>>(wUV, tUV, CKV_, NH_*HD_, NH_*HD_);
  wtrans<<<dim3(CQ_ / 32, HID_ / 32), tb, 0, stream>>>(wDQ, tDQ, HID_, CQ_, CQ_);
  wtrans<<<dim3((NH_*HD_) / 32, CQ_ / 32), tb, 0, stream>>>(wUQ, tUQ, CQ_, NH_*HD_, NH_*HD_);
  wtrans<<<dim3((NH_*RD_) / 32, CQ_ / 32), tb, 0, stream>>>(wQR, tQR, CQ_, NH_*RD_, NH_*RD_);
  wtrans<<<dim3(128 / 32, HID_ / 32), tb, 0, stream>>>(wKR, tKR, HID_, RD_, 128);
  wtrans<<<dim3((NH_*HD_) / 32, HID_ / 32), tb, 0, stream>>>(wO, tWO, HID_, NH_*HD_, NH_*HD_);

  // 3. projections
  gemm_bt<0><<<dim3(CKV_ / 128, M_ / 128), 256, 0, stream>>>(hsb, tDKV, cKV, M_, CKV_, HID_);
  gemm_bt<0><<<dim3(CQ_ / 128, M_ / 128), 256, 0, stream>>>(hsb, tDQ, cQ, M_, CQ_, HID_);
  gemm_bt<1><<<dim3((NH_*HD_) / 128, M_ / 128), 256, 0, stream>>>(cKV, tUK, kbuf, M_, NH_*HD_, CKV_);
  gemm_bt<2><<<dim3((NH_*HD_) / 128, M_ / 128), 256, 0, stream>>>(cKV, tUV, vTb, M_, NH_*HD_, CKV_);
  gemm_bt<1><<<dim3((NH_*HD_) / 128, M_ / 128), 256, 0, stream>>>(cQ, tUQ, qbuf, M_, NH_*HD_, CQ_);
  gemm_bt<0><<<dim3((NH_*RD_) / 128, M_ / 128), 256, 0, stream>>>(cQ, tQR, qRt, M_, NH_*RD_, CQ_);
  gemm_bt<0><<<dim3(128 / 128, M_ / 128), 256, 0, stream>>>(hsb, tKR, kRt, M_, 128, HID_);

  // 4. RoPE
  rope_q<<<(M_ * NH_ * RD_) / 256, 256, 0, stream>>>(qRt, qbuf);
  rope_k<<<(M_ * RD_) / 256, 256, 0, stream>>>(kRt, kbuf);

  // 5. attention (QBLK=128, KVBLK=64, swapped-QK softmax)
  attn_kern<<<dim3(S_ / 128, B_ * NH_), 256, 0, stream>>>(qbuf, kbuf, vTb, aout);

  // 6. output projection (fp32 out)
  gemm_bt<3><<<dim3((NH_*HD_) / 128, M_ / 128), 256, 0, stream>>>(aout, tWO, out, M_, NH_*HD_, HID_);
}

// Round 6
// 469.095 us; speedup vs baseline: 1.2948x; 1.1765x over previous
//
#include <hip/hip_runtime.h>
#include <hip/hip_bf16.h>

typedef __bf16 bf16x8 __attribute__((ext_vector_type(8)));
typedef float f32x4 __attribute__((ext_vector_type(4)));
typedef float f32x16 __attribute__((ext_vector_type(16)));
using BF = __hip_bfloat16;

// Problem constants
constexpr int B_   = 2;
constexpr int S_   = 2048;
constexpr int NH_  = 16;
constexpr int HD_  = 128;
constexpr int HID_ = 2048;
constexpr int CKV_ = 512;
constexpr int CQ_  = 1024;
constexpr int RD_  = 64;
constexpr int M_   = B_ * S_;     // 4096 tokens
constexpr int DQK_ = HD_ + RD_;   // 192

__device__ __forceinline__ f32x4 mfma16(bf16x8 a, bf16x8 b, f32x4 c) {
  return __builtin_amdgcn_mfma_f32_16x16x32_bf16(a, b, c, 0, 0, 0);
}
__device__ __forceinline__ f32x16 mfma32(bf16x8 a, bf16x8 b, f32x16 c) {
  return __builtin_amdgcn_mfma_f32_32x32x16_bf16(a, b, c, 0, 0, 0);
}
__device__ __forceinline__ unsigned cvtpk(float a, float b) {
  unsigned r;
  asm("v_cvt_pk_bf16_f32 %0, %1, %2" : "=v"(r) : "v"(a), "v"(b));
  return r;
}
// (x,y) -> x' = low-half frag, y' = high-half frag (lane<32 keeps x, gets partner y; etc.)
__device__ __forceinline__ void plswap(unsigned& x, unsigned& y, bool hi) {
#if __has_builtin(__builtin_amdgcn_permlane32_swap)
  typedef unsigned u32x2 __attribute__((ext_vector_type(2)));
  u32x2 r = __builtin_amdgcn_permlane32_swap(x, y, false, false);
  x = r[0];
  y = r[1];
#else
  unsigned sx = (unsigned)__shfl_xor((int)x, 32, 64);
  unsigned sy = (unsigned)__shfl_xor((int)y, 32, 64);
  unsigned nx = hi ? sy : x;
  unsigned ny = hi ? y : sx;
  x = nx;
  y = ny;
#endif
}

// ---------------- fp32 -> bf16 convert (vectorized) ----------------
__global__ __launch_bounds__(256) void f2b_kern(const float* __restrict__ in,
                                                BF* __restrict__ out, int n4) {
  int i = blockIdx.x * 256 + threadIdx.x;
  if (i >= n4) return;
  float4 v = reinterpret_cast<const float4*>(in)[i];
  BF o[4] = {__float2bfloat16(v.x), __float2bfloat16(v.y),
             __float2bfloat16(v.z), __float2bfloat16(v.w)};
  reinterpret_cast<uint2*>(out)[i] = *reinterpret_cast<uint2*>(o);
}

// ------------- tiled transpose fp32 (K,N) -> bf16 (Npad,K), zero-pad n>=N -------------
__global__ __launch_bounds__(256) void wtrans(const float* __restrict__ in,
                                              BF* __restrict__ out,
                                              int K, int N, int Npad) {
  __shared__ float t[32][33];
  int n0 = blockIdx.x * 32, k0 = blockIdx.y * 32;
  int tx = threadIdx.x, ty = threadIdx.y;
#pragma unroll
  for (int j = 0; j < 4; j++) {
    int k = k0 + ty + j * 8, n = n0 + tx;
    t[ty + j * 8][tx] = (n < N) ? in[(size_t)k * N + n] : 0.f;
  }
  __syncthreads();
#pragma unroll
  for (int j = 0; j < 4; j++) {
    int n = n0 + ty + j * 8, k = k0 + tx;
    out[(size_t)n * K + k] = __float2bfloat16(t[tx][ty + j * 8]);
  }
}

// ---------------- GEMM: C = A(M,K) x Bt(N,K)^T, bf16 in, fp32 acc ----------------
// 128x128 tile, BK=32, 256 threads = 4 waves (2x2), each wave 64x64 (4x4 frags).
template <int MODE>
__global__ __launch_bounds__(256) void gemm_bt(const BF* __restrict__ A,
                                               const BF* __restrict__ Bt,
                                               void* __restrict__ C,
                                               int M, int N, int K) {
  __shared__ BF As[128][32];
  __shared__ BF Bs[128][32];
  const int tid = threadIdx.x;
  const int w = tid >> 6, l = tid & 63;
  const int lr = l & 15, lg = l >> 4;
  const int wr = w >> 1, wc = w & 1;
  const int m0 = blockIdx.y * 128, n0 = blockIdx.x * 128;

  f32x4 acc[4][4];
#pragma unroll
  for (int m = 0; m < 4; m++)
#pragma unroll
    for (int n = 0; n < 4; n++) acc[m][n] = (f32x4){0.f, 0.f, 0.f, 0.f};

  for (int k0 = 0; k0 < K; k0 += 32) {
    __syncthreads();
#pragma unroll
    for (int j = 0; j < 2; j++) {
      int idx = tid + j * 256;
      int row = idx >> 2, seg = idx & 3;
      *reinterpret_cast<bf16x8*>(&As[row][seg * 8]) =
          *reinterpret_cast<const bf16x8*>(A + (size_t)(m0 + row) * K + k0 + seg * 8);
      *reinterpret_cast<bf16x8*>(&Bs[row][seg * 8]) =
          *reinterpret_cast<const bf16x8*>(Bt + (size_t)(n0 + row) * K + k0 + seg * 8);
    }
    __syncthreads();
    bf16x8 af[4], bfr[4];
#pragma unroll
    for (int m = 0; m < 4; m++)
      af[m] = *reinterpret_cast<const bf16x8*>(&As[wr * 64 + m * 16 + lr][lg * 8]);
#pragma unroll
    for (int n = 0; n < 4; n++)
      bfr[n] = *reinterpret_cast<const bf16x8*>(&Bs[wc * 64 + n * 16 + lr][lg * 8]);
#pragma unroll
    for (int m = 0; m < 4; m++)
#pragma unroll
      for (int n = 0; n < 4; n++) acc[m][n] = mfma16(af[m], bfr[n], acc[m][n]);
  }

  // epilogue: C/D layout col = lane&15, row = (lane>>4)*4 + j  (m89-verified)
#pragma unroll
  for (int m = 0; m < 4; m++) {
#pragma unroll
    for (int n = 0; n < 4; n++) {
#pragma unroll
      for (int j = 0; j < 4; j++) {
        int row = m0 + wr * 64 + m * 16 + lg * 4 + j;
        int col = n0 + wc * 64 + n * 16 + lr;
        float v = acc[m][n][j];
        if constexpr (MODE == 0) {
          ((BF*)C)[(size_t)row * N + col] = __float2bfloat16(v);
        } else if constexpr (MODE == 1) {
          int b = row >> 11, s = row & 2047, h = col >> 7, d = col & 127;
          ((BF*)C)[((size_t)(b * 16 + h) * 2048 + s) * 192 + d] = __float2bfloat16(v);
        } else if constexpr (MODE == 2) {
          int b = row >> 11, s = row & 2047, h = col >> 7, d = col & 127;
          ((BF*)C)[((size_t)(b * 16 + h) * 128 + d) * 2048 + s] = __float2bfloat16(v);
        } else {
          ((float*)C)[(size_t)row * N + col] = v;
        }
      }
    }
  }
}

// ---------------- RoPE ----------------
__global__ __launch_bounds__(256) void rope_q(const BF* __restrict__ qr, BF* __restrict__ qb) {
  int idx = blockIdx.x * 256 + threadIdx.x;  // 4096*16*64
  int d = idx & 63, h = (idx >> 6) & 15, m = idx >> 10;
  int s = m & 2047, b = m >> 11;
  float x = __bfloat162float(qr[(size_t)(m << 10) + (h << 6) + d]);
  float other = __bfloat162float(qr[(size_t)(m << 10) + (h << 6) + (d ^ 32)]);
  float rot = (d < 32) ? -other : other;
  int di = d & 31;
  float arg = (float)s * powf(10000.f, -(float)di / 32.0f);
  float c = cosf(arg), sn = sinf(arg);
  qb[((size_t)(b * 16 + h) * 2048 + s) * 192 + 128 + d] = __float2bfloat16(x * c + rot * sn);
}

__global__ __launch_bounds__(256) void rope_k(const BF* __restrict__ kr, BF* __restrict__ kb) {
  int idx = blockIdx.x * 256 + threadIdx.x;  // 4096*64
  int d = idx & 63, m = idx >> 6;
  int s = m & 2047, b = m >> 11;
  float x = __bfloat162float(kr[(size_t)m * 128 + d]);
  float other = __bfloat162float(kr[(size_t)m * 128 + (d ^ 32)]);
  float rot = (d < 32) ? -other : other;
  int di = d & 31;
  float arg = (float)s * powf(10000.f, -(float)di / 32.0f);
  float val = x * cosf(arg) + rot * sinf(arg);
  BF v = __float2bfloat16(val);
#pragma unroll
  for (int h = 0; h < 16; h++)
    kb[((size_t)(b * 16 + h) * 2048 + s) * 192 + 128 + d] = v;
}

// ---------------- flash attention v4: 32x32 MFMA, in-register P ----------------
// QBLK=128 (4 waves x 32 q), KVBLK=64. S^T = mfma32(K, Q): lane holds 32 of 64
// S-values for its OWN q (=lane&31); hi-half (lane>>5) holds the complement.
// Softmax in-lane + 1 shuffle. P -> bf16 frags via cvt_pk + permlane32_swap
// (zero LDS). PV: O^T = mfma32(V, P): output col = lane&31 = q -> rescale and
// 1/l all lane-local. LDS only K/V tiles, XOR-swizzled (slot ^= row&7).
__global__ __launch_bounds__(256, 2) void attn_kern(const BF* __restrict__ qb,
                                                    const BF* __restrict__ kb,
                                                    const BF* __restrict__ vT,
                                                    BF* __restrict__ o) {
  const int bh = blockIdx.y;
  const int q0 = ((int)gridDim.x - 1 - (int)blockIdx.x) * 128;  // longest first
  const int tid = threadIdx.x;
  const int w = tid >> 6, l = tid & 63;
  const int lo5 = l & 31;
  const int hi = l >> 5;
  const int l7 = l & 7;

  // Ks: 64 x 192 bf16 = 24576 B (24 slots/row, swizzled). Vs: 128 x 64 = 16384 B.
  __shared__ __align__(16) char smem[40960];
  BF* Ks = (BF*)smem;
  BF* Vs = (BF*)(smem + 24576);

  const int q = q0 + w * 32 + lo5;   // this lane's q-row
  const int qmax = q0 + w * 32 + 31; // wave-uniform

  // Q fragments: B-operand, 12 k-steps of 16 (D=192)
  bf16x8 aq[12];
  {
    const BF* qrow = qb + ((size_t)bh * 2048 + q) * 192;
#pragma unroll
    for (int kst = 0; kst < 12; kst++)
      aq[kst] = *reinterpret_cast<const bf16x8*>(qrow + kst * 16 + hi * 8);
  }

  f32x16 Oacc[4];
#pragma unroll
  for (int dt = 0; dt < 4; dt++)
#pragma unroll
    for (int r = 0; r < 16; r++) Oacc[dt][r] = 0.f;
  float mrow = -3e38f, lrow = 0.f;

  const float scale = 0.07216878364870323f;  // 1/sqrt(192)
  const int nch = (q0 + 128) >> 6;

  for (int ch = 0; ch < nch; ch++) {
    const int c0 = ch << 6;
    __syncthreads();
    // stage Ks (64x192): 1536 16B-slots, swizzled: phys slot sp holds logical sp^(row&7)
#pragma unroll
    for (int j2 = 0; j2 < 6; j2++) {
      int D = tid + j2 * 256;
      int row = D / 24, sp = D % 24;
      int sl = sp ^ (row & 7);
      *reinterpret_cast<bf16x8*>(Ks + row * 192 + sp * 8) =
          *reinterpret_cast<const bf16x8*>(kb + ((size_t)bh * 2048 + c0 + row) * 192 + sl * 8);
    }
    // stage Vs (128x64): 1024 slots
#pragma unroll
    for (int j2 = 0; j2 < 4; j2++) {
      int D = tid + j2 * 256;
      int row = D >> 3, sp = D & 7;
      int sl = sp ^ (row & 7);
      *reinterpret_cast<bf16x8*>(Vs + row * 64 + sp * 8) =
          *reinterpret_cast<const bf16x8*>(vT + ((size_t)bh * 128 + row) * 2048 + c0 + sl * 8);
    }
    __syncthreads();

    // QK^T (swapped): sf[t] = S^T[key tile t][q], 2 tiles x 12 ksteps, 2 acc chains each
    f32x16 sf[2];
#pragma unroll
    for (int t = 0; t < 2; t++) {
      if (c0 + t * 32 <= qmax) {
        f32x16 a0, a1;
#pragma unroll
        for (int r = 0; r < 16; r++) { a0[r] = 0.f; a1[r] = 0.f; }
#pragma unroll
        for (int kst = 0; kst < 12; kst++) {
          bf16x8 kfr = *reinterpret_cast<const bf16x8*>(
              Ks + (t * 32 + lo5) * 192 + (((kst * 2 + hi) ^ l7) * 8));
          if (kst & 1) a1 = mfma32(kfr, aq[kst], a1);
          else         a0 = mfma32(kfr, aq[kst], a0);
        }
        sf[t] = a0 + a1;
      } else {
#pragma unroll
        for (int r = 0; r < 16; r++) sf[t][r] = 0.f;
      }
    }

    // scale + causal mask + in-lane max (keys for this lane: t*32+(r&3)+8*(r>>2)+4*hi)
    float mx = -3e38f;
#pragma unroll
    for (int t = 0; t < 2; t++) {
#pragma unroll
      for (int r = 0; r < 16; r++) {
        int key = c0 + t * 32 + (r & 3) + 8 * (r >> 2) + 4 * hi;
        float v = sf[t][r] * scale;
        v = (key <= q) ? v : -1e30f;
        sf[t][r] = v;
        mx = fmaxf(mx, v);
      }
    }
    mx = fmaxf(mx, __shfl_xor(mx, 32, 64));  // combine complementary key halves
    float mnew = fmaxf(mrow, mx);
    float corr = __expf(mrow - mnew);
    mrow = mnew;
    float psum = 0.f;
#pragma unroll
    for (int t = 0; t < 2; t++)
#pragma unroll
      for (int r = 0; r < 16; r++) {
        float p = __expf(sf[t][r] - mnew);
        sf[t][r] = p;
        psum += p;
      }
    psum += __shfl_xor(psum, 32, 64);
    lrow = lrow * corr + psum;
#pragma unroll
    for (int dt = 0; dt < 4; dt++) Oacc[dt] *= corr;

    // P -> bf16 B-frags, in-register: 4 cvt_pk + 2 permlane32_swap per 16-key step
    bf16x8 pb[4];
#pragma unroll
    for (int ks = 0; ks < 4; ks++) {
      if (c0 + ks * 16 > qmax) continue;
      int t = ks >> 1, base = (ks & 1) * 8;
      unsigned Xa = cvtpk(sf[t][base + 0], sf[t][base + 1]);
      unsigned Xb = cvtpk(sf[t][base + 2], sf[t][base + 3]);
      unsigned Ya = cvtpk(sf[t][base + 4], sf[t][base + 5]);
      unsigned Yb = cvtpk(sf[t][base + 6], sf[t][base + 7]);
      plswap(Xa, Ya, hi != 0);
      plswap(Xb, Yb, hi != 0);
      union { unsigned u[4]; bf16x8 v; } pk_;
      pk_.u[0] = Xa; pk_.u[1] = Xb; pk_.u[2] = Ya; pk_.u[3] = Yb;
      pb[ks] = pk_.v;
    }

    // PV: O^T[d][q] += V x P, 4 d-tiles x 4 ksteps
#pragma unroll
    for (int ks = 0; ks < 4; ks++) {
      if (c0 + ks * 16 > qmax) continue;
#pragma unroll
      for (int dt = 0; dt < 4; dt++) {
        bf16x8 vfr = *reinterpret_cast<const bf16x8*>(
            Vs + (dt * 32 + lo5) * 64 + (((ks * 2 + hi) ^ l7) * 8));
        Oacc[dt] = mfma32(vfr, pb[ks], Oacc[dt]);
      }
    }
  }

  // epilogue: normalize (lane-local l), transpose via LDS, coalesced store
  __syncthreads();  // all PV done before smem reuse
  BF* Osh = (BF*)smem;  // [128 rows][136 elems] (pad 8 vs 128 to spread banks)
  float rinv = 1.0f / lrow;
  const int orow = w * 32 + lo5;
#pragma unroll
  for (int dt = 0; dt < 4; dt++) {
#pragma unroll
    for (int g = 0; g < 4; g++) {
      unsigned d0 = cvtpk(Oacc[dt][g * 4 + 0] * rinv, Oacc[dt][g * 4 + 1] * rinv);
      unsigned d1 = cvtpk(Oacc[dt][g * 4 + 2] * rinv, Oacc[dt][g * 4 + 3] * rinv);
      uint2 pr; pr.x = d0; pr.y = d1;
      *reinterpret_cast<uint2*>(Osh + orow * 136 + dt * 32 + g * 8 + hi * 4) = pr;
    }
  }
  __syncthreads();
  const int b = bh >> 4, h = bh & 15;
  const int cb = tid & 15, rb = tid >> 4;
#pragma unroll
  for (int rr = 0; rr < 8; rr++) {
    int row = rb + rr * 16;
    bf16x8 v = *reinterpret_cast<const bf16x8*>(Osh + row * 136 + cb * 8);
    *reinterpret_cast<bf16x8*>(o + ((size_t)(b * 2048 + q0 + row)) * 2048 + h * 128 + cb * 8) = v;
  }
}

extern "C" void kernel_launch(void* const* d_in, const int* in_sizes, int n_in,
                              void* d_out, int out_size, void* d_ws, size_t ws_size,
                              hipStream_t stream) {
  const float* hs   = (const float*)d_in[0];
  const float* wDKV = (const float*)d_in[2];
  const float* wUK  = (const float*)d_in[3];
  const float* wUV  = (const float*)d_in[4];
  const float* wDQ  = (const float*)d_in[5];
  const float* wUQ  = (const float*)d_in[6];
  const float* wQR  = (const float*)d_in[7];
  const float* wKR  = (const float*)d_in[8];
  const float* wO   = (const float*)d_in[9];
  float* out = (float*)d_out;

  char* ws = (char*)d_ws;
  size_t off = 0;
  auto alloc = [&](size_t bytes) -> char* {
    char* p = ws + off;
    off += (bytes + 255) & ~(size_t)255;
    return p;
  };
  BF* hsb   = (BF*)alloc((size_t)M_ * HID_ * 2);        // 4096x2048
  BF* tDKV  = (BF*)alloc((size_t)CKV_ * HID_ * 2);      // (512,2048)
  BF* tUK   = (BF*)alloc((size_t)(NH_*HD_) * CKV_ * 2); // (2048,512)
  BF* tUV   = (BF*)alloc((size_t)(NH_*HD_) * CKV_ * 2); // (2048,512)
  BF* tDQ   = (BF*)alloc((size_t)CQ_ * HID_ * 2);       // (1024,2048)
  BF* tUQ   = (BF*)alloc((size_t)(NH_*HD_) * CQ_ * 2);  // (2048,1024)
  BF* tQR   = (BF*)alloc((size_t)(NH_*RD_) * CQ_ * 2);  // (1024,1024)
  BF* tKR   = (BF*)alloc((size_t)128 * HID_ * 2);       // (128,2048) padded
  BF* tWO   = (BF*)alloc((size_t)HID_ * (NH_*HD_) * 2); // (2048,2048)
  BF* cKV   = (BF*)alloc((size_t)M_ * CKV_ * 2);
  BF* cQ    = (BF*)alloc((size_t)M_ * CQ_ * 2);
  BF* qbuf  = (BF*)alloc((size_t)B_ * NH_ * S_ * DQK_ * 2);
  BF* kbuf  = (BF*)alloc((size_t)B_ * NH_ * S_ * DQK_ * 2);
  BF* vTb   = (BF*)alloc((size_t)B_ * NH_ * HD_ * S_ * 2);
  BF* qRt   = (BF*)alloc((size_t)M_ * (NH_*RD_) * 2);
  BF* kRt   = (BF*)alloc((size_t)M_ * 128 * 2);
  BF* aout  = (BF*)alloc((size_t)M_ * (NH_*HD_) * 2);

  // 1. hidden -> bf16
  f2b_kern<<<(M_ * HID_ / 4 + 255) / 256, 256, 0, stream>>>(hs, hsb, M_ * HID_ / 4);

  // 2. weight transposes (fp32 (K,N) -> bf16 (Npad,K))
  dim3 tb(32, 8);
  wtrans<<<dim3(CKV_ / 32, HID_ / 32), tb, 0, stream>>>(wDKV, tDKV, HID_, CKV_, CKV_);
  wtrans<<<dim3((NH_*HD_) / 32, CKV_ / 32), tb, 0, stream>>>(wUK, tUK, CKV_, NH_*HD_, NH_*HD_);
  wtrans<<<dim3((NH_*HD_) / 32, CKV_ / 32), tb, 0, stream>>>(wUV, tUV, CKV_, NH_*HD_, NH_*HD_);
  wtrans<<<dim3(CQ_ / 32, HID_ / 32), tb, 0, stream>>>(wDQ, tDQ, HID_, CQ_, CQ_);
  wtrans<<<dim3((NH_*HD_) / 32, CQ_ / 32), tb, 0, stream>>>(wUQ, tUQ, CQ_, NH_*HD_, NH_*HD_);
  wtrans<<<dim3((NH_*RD_) / 32, CQ_ / 32), tb, 0, stream>>>(wQR, tQR, CQ_, NH_*RD_, NH_*RD_);
  wtrans<<<dim3(128 / 32, HID_ / 32), tb, 0, stream>>>(wKR, tKR, HID_, RD_, 128);
  wtrans<<<dim3((NH_*HD_) / 32, HID_ / 32), tb, 0, stream>>>(wO, tWO, HID_, NH_*HD_, NH_*HD_);

  // 3. projections
  gemm_bt<0><<<dim3(CKV_ / 128, M_ / 128), 256, 0, stream>>>(hsb, tDKV, cKV, M_, CKV_, HID_);
  gemm_bt<0><<<dim3(CQ_ / 128, M_ / 128), 256, 0, stream>>>(hsb, tDQ, cQ, M_, CQ_, HID_);
  gemm_bt<1><<<dim3((NH_*HD_) / 128, M_ / 128), 256, 0, stream>>>(cKV, tUK, kbuf, M_, NH_*HD_, CKV_);
  gemm_bt<2><<<dim3((NH_*HD_) / 128, M_ / 128), 256, 0, stream>>>(cKV, tUV, vTb, M_, NH_*HD_, CKV_);
  gemm_bt<1><<<dim3((NH_*HD_) / 128, M_ / 128), 256, 0, stream>>>(cQ, tUQ, qbuf, M_, NH_*HD_, CQ_);
  gemm_bt<0><<<dim3((NH_*RD_) / 128, M_ / 128), 256, 0, stream>>>(cQ, tQR, qRt, M_, NH_*RD_, CQ_);
  gemm_bt<0><<<dim3(128 / 128, M_ / 128), 256, 0, stream>>>(hsb, tKR, kRt, M_, 128, HID_);

  // 4. RoPE
  rope_q<<<(M_ * NH_ * RD_) / 256, 256, 0, stream>>>(qRt, qbuf);
  rope_k<<<(M_ * RD_) / 256, 256, 0, stream>>>(kRt, kbuf);

  // 5. attention (QBLK=128, KVBLK=64, 32x32 MFMA, in-register P)
  attn_kern<<<dim3(S_ / 128, B_ * NH_), 256, 0, stream>>>(qbuf, kbuf, vTb, aout);

  // 6. output projection (fp32 out)
  gemm_bt<3><<<dim3((NH_*HD_) / 128, M_ / 128), 256, 0, stream>>>(aout, tWO, out, M_, NH_*HD_, HID_);
}

// Round 7
// 456.904 us; speedup vs baseline: 1.3293x; 1.0267x over previous
//
#include <hip/hip_runtime.h>
#include <hip/hip_bf16.h>

typedef __bf16 bf16x8 __attribute__((ext_vector_type(8)));
typedef float f32x4 __attribute__((ext_vector_type(4)));
typedef float f32x16 __attribute__((ext_vector_type(16)));
using BF = __hip_bfloat16;

// Problem constants
constexpr int B_   = 2;
constexpr int S_   = 2048;
constexpr int NH_  = 16;
constexpr int HD_  = 128;
constexpr int HID_ = 2048;
constexpr int CKV_ = 512;
constexpr int CQ_  = 1024;
constexpr int RD_  = 64;
constexpr int M_   = B_ * S_;     // 4096 tokens
constexpr int DQK_ = HD_ + RD_;   // 192

__device__ __forceinline__ f32x4 mfma16(bf16x8 a, bf16x8 b, f32x4 c) {
  return __builtin_amdgcn_mfma_f32_16x16x32_bf16(a, b, c, 0, 0, 0);
}
__device__ __forceinline__ f32x16 mfma32(bf16x8 a, bf16x8 b, f32x16 c) {
  return __builtin_amdgcn_mfma_f32_32x32x16_bf16(a, b, c, 0, 0, 0);
}
__device__ __forceinline__ unsigned cvtpk(float a, float b) {
  unsigned r;
  asm("v_cvt_pk_bf16_f32 %0, %1, %2" : "=v"(r) : "v"(a), "v"(b));
  return r;
}
// async global->LDS, 16B per lane; dest must be linear in lane order (G21)
__device__ __forceinline__ void gload16(const void* g, void* lds) {
  __builtin_amdgcn_global_load_lds((const __attribute__((address_space(1))) void*)g,
                                   (__attribute__((address_space(3))) void*)lds,
                                   16, 0, 0);
}
// (x,y) -> x' = low-half frag, y' = high-half frag
__device__ __forceinline__ void plswap(unsigned& x, unsigned& y, bool hi) {
#if __has_builtin(__builtin_amdgcn_permlane32_swap)
  typedef unsigned u32x2 __attribute__((ext_vector_type(2)));
  u32x2 r = __builtin_amdgcn_permlane32_swap(x, y, false, false);
  x = r[0];
  y = r[1];
#else
  unsigned sx = (unsigned)__shfl_xor((int)x, 32, 64);
  unsigned sy = (unsigned)__shfl_xor((int)y, 32, 64);
  unsigned nx = hi ? sy : x;
  unsigned ny = hi ? y : sx;
  x = nx;
  y = ny;
#endif
}

// ---------------- fp32 -> bf16 convert (vectorized) ----------------
__global__ __launch_bounds__(256) void f2b_kern(const float* __restrict__ in,
                                                BF* __restrict__ out, int n4) {
  int i = blockIdx.x * 256 + threadIdx.x;
  if (i >= n4) return;
  float4 v = reinterpret_cast<const float4*>(in)[i];
  BF o[4] = {__float2bfloat16(v.x), __float2bfloat16(v.y),
             __float2bfloat16(v.z), __float2bfloat16(v.w)};
  reinterpret_cast<uint2*>(out)[i] = *reinterpret_cast<uint2*>(o);
}

// ------------- tiled transpose fp32 (K,N) -> bf16 (Npad,K), zero-pad n>=N -------------
__global__ __launch_bounds__(256) void wtrans(const float* __restrict__ in,
                                              BF* __restrict__ out,
                                              int K, int N, int Npad) {
  __shared__ float t[32][33];
  int n0 = blockIdx.x * 32, k0 = blockIdx.y * 32;
  int tx = threadIdx.x, ty = threadIdx.y;
#pragma unroll
  for (int j = 0; j < 4; j++) {
    int k = k0 + ty + j * 8, n = n0 + tx;
    t[ty + j * 8][tx] = (n < N) ? in[(size_t)k * N + n] : 0.f;
  }
  __syncthreads();
#pragma unroll
  for (int j = 0; j < 4; j++) {
    int n = n0 + ty + j * 8, k = k0 + tx;
    out[(size_t)n * K + k] = __float2bfloat16(t[tx][ty + j * 8]);
  }
}

// ---------------- GEMM: C = A(M,K) x Bt(N,K)^T, bf16 in, fp32 acc ----------------
// m97 structure: 128x128 tile, BK=32, global_load_lds(16B) staging,
// 256 threads = 4 waves (2x2), each wave 64x64 (4x4 frags).
template <int MODE>
__global__ __launch_bounds__(256) void gemm_bt(const BF* __restrict__ A,
                                               const BF* __restrict__ Bt,
                                               void* __restrict__ C,
                                               int M, int N, int K) {
  __shared__ BF As[128][32];
  __shared__ BF Bs[128][32];
  const int tid = threadIdx.x;
  const int w = tid >> 6, l = tid & 63;
  const int lr = l & 15, lg = l >> 4;
  const int wr = w >> 1, wc = w & 1;
  const int m0 = blockIdx.y * 128, n0 = blockIdx.x * 128;

  f32x4 acc[4][4];
#pragma unroll
  for (int m = 0; m < 4; m++)
#pragma unroll
    for (int n = 0; n < 4; n++) acc[m][n] = (f32x4){0.f, 0.f, 0.f, 0.f};

  for (int k0 = 0; k0 < K; k0 += 32) {
    __syncthreads();
    // stage via async global->LDS: LDS dest offset = idx*16B (linear in lane)
#pragma unroll
    for (int j = 0; j < 2; j++) {
      int idx = tid + j * 256;
      int row = idx >> 2, seg = idx & 3;
      gload16(A + (size_t)(m0 + row) * K + k0 + seg * 8, &As[0][0] + idx * 8);
      gload16(Bt + (size_t)(n0 + row) * K + k0 + seg * 8, &Bs[0][0] + idx * 8);
    }
    __syncthreads();
    bf16x8 af[4], bfr[4];
#pragma unroll
    for (int m = 0; m < 4; m++)
      af[m] = *reinterpret_cast<const bf16x8*>(&As[wr * 64 + m * 16 + lr][lg * 8]);
#pragma unroll
    for (int n = 0; n < 4; n++)
      bfr[n] = *reinterpret_cast<const bf16x8*>(&Bs[wc * 64 + n * 16 + lr][lg * 8]);
#pragma unroll
    for (int m = 0; m < 4; m++)
#pragma unroll
      for (int n = 0; n < 4; n++) acc[m][n] = mfma16(af[m], bfr[n], acc[m][n]);
  }

  // epilogue: C/D layout col = lane&15, row = (lane>>4)*4 + j  (m89-verified)
#pragma unroll
  for (int m = 0; m < 4; m++) {
#pragma unroll
    for (int n = 0; n < 4; n++) {
#pragma unroll
      for (int j = 0; j < 4; j++) {
        int row = m0 + wr * 64 + m * 16 + lg * 4 + j;
        int col = n0 + wc * 64 + n * 16 + lr;
        float v = acc[m][n][j];
        if constexpr (MODE == 0) {
          ((BF*)C)[(size_t)row * N + col] = __float2bfloat16(v);
        } else if constexpr (MODE == 1) {
          int b = row >> 11, s = row & 2047, h = col >> 7, d = col & 127;
          ((BF*)C)[((size_t)(b * 16 + h) * 2048 + s) * 192 + d] = __float2bfloat16(v);
        } else if constexpr (MODE == 2) {
          int b = row >> 11, s = row & 2047, h = col >> 7, d = col & 127;
          ((BF*)C)[((size_t)(b * 16 + h) * 128 + d) * 2048 + s] = __float2bfloat16(v);
        } else {
          ((float*)C)[(size_t)row * N + col] = v;
        }
      }
    }
  }
}

// ---------------- RoPE ----------------
__global__ __launch_bounds__(256) void rope_q(const BF* __restrict__ qr, BF* __restrict__ qb) {
  int idx = blockIdx.x * 256 + threadIdx.x;  // 4096*16*64
  int d = idx & 63, h = (idx >> 6) & 15, m = idx >> 10;
  int s = m & 2047, b = m >> 11;
  float x = __bfloat162float(qr[(size_t)(m << 10) + (h << 6) + d]);
  float other = __bfloat162float(qr[(size_t)(m << 10) + (h << 6) + (d ^ 32)]);
  float rot = (d < 32) ? -other : other;
  int di = d & 31;
  float arg = (float)s * powf(10000.f, -(float)di / 32.0f);
  float c = cosf(arg), sn = sinf(arg);
  qb[((size_t)(b * 16 + h) * 2048 + s) * 192 + 128 + d] = __float2bfloat16(x * c + rot * sn);
}

__global__ __launch_bounds__(256) void rope_k(const BF* __restrict__ kr, BF* __restrict__ kb) {
  int idx = blockIdx.x * 256 + threadIdx.x;  // 4096*64
  int d = idx & 63, m = idx >> 6;
  int s = m & 2047, b = m >> 11;
  float x = __bfloat162float(kr[(size_t)m * 128 + d]);
  float other = __bfloat162float(kr[(size_t)m * 128 + (d ^ 32)]);
  float rot = (d < 32) ? -other : other;
  int di = d & 31;
  float arg = (float)s * powf(10000.f, -(float)di / 32.0f);
  float val = x * cosf(arg) + rot * sinf(arg);
  BF v = __float2bfloat16(val);
#pragma unroll
  for (int h = 0; h < 16; h++)
    kb[((size_t)(b * 16 + h) * 2048 + s) * 192 + 128 + d] = v;
}

// ---------------- flash attention v4.1: 32x32 MFMA, in-register P, gload_lds ----------------
// QBLK=128 (4 waves x 32 q), KVBLK=64. S^T = mfma32(K, Q): lane holds 32 of 64
// S-values for its OWN q (=lane&31). Softmax in-lane + 1 shuffle. P -> bf16 via
// cvt_pk + permlane32_swap (zero LDS). PV: O^T = mfma32(V, P). K/V staged via
// global_load_lds with source-side XOR swizzle (dest linear in lane, G21).
__global__ __launch_bounds__(256, 2) void attn_kern(const BF* __restrict__ qb,
                                                    const BF* __restrict__ kb,
                                                    const BF* __restrict__ vT,
                                                    BF* __restrict__ o) {
  const int bh = blockIdx.y;
  const int q0 = ((int)gridDim.x - 1 - (int)blockIdx.x) * 128;  // longest first
  const int tid = threadIdx.x;
  const int w = tid >> 6, l = tid & 63;
  const int lo5 = l & 31;
  const int hi = l >> 5;
  const int l7 = l & 7;

  // Ks: 64 x 192 bf16 = 24576 B (24 slots/row, swizzled). Vs: 128 x 64 = 16384 B.
  __shared__ __align__(16) char smem[40960];
  BF* Ks = (BF*)smem;
  BF* Vs = (BF*)(smem + 24576);

  const int q = q0 + w * 32 + lo5;   // this lane's q-row
  const int qmax = q0 + w * 32 + 31; // wave-uniform

  // Q fragments: B-operand, 12 k-steps of 16 (D=192)
  bf16x8 aq[12];
  {
    const BF* qrow = qb + ((size_t)bh * 2048 + q) * 192;
#pragma unroll
    for (int kst = 0; kst < 12; kst++)
      aq[kst] = *reinterpret_cast<const bf16x8*>(qrow + kst * 16 + hi * 8);
  }

  f32x16 Oacc[4];
#pragma unroll
  for (int dt = 0; dt < 4; dt++)
#pragma unroll
    for (int r = 0; r < 16; r++) Oacc[dt][r] = 0.f;
  float mrow = -3e38f, lrow = 0.f;

  const float scale = 0.07216878364870323f;  // 1/sqrt(192)
  const int nch = (q0 + 128) >> 6;

  for (int ch = 0; ch < nch; ch++) {
    const int c0 = ch << 6;
    __syncthreads();
    // stage Ks (64x192): phys slot sp holds logical sp^(row&7); dest = D*16B linear
#pragma unroll
    for (int j2 = 0; j2 < 6; j2++) {
      int D = tid + j2 * 256;
      int row = D / 24, sp = D % 24;
      int sl = sp ^ (row & 7);
      gload16(kb + ((size_t)bh * 2048 + c0 + row) * 192 + sl * 8, Ks + D * 8);
    }
    // stage Vs (128x64)
#pragma unroll
    for (int j2 = 0; j2 < 4; j2++) {
      int D = tid + j2 * 256;
      int row = D >> 3, sp = D & 7;
      int sl = sp ^ (row & 7);
      gload16(vT + ((size_t)bh * 128 + row) * 2048 + c0 + sl * 8, Vs + D * 8);
    }
    __syncthreads();

    // QK^T (swapped): sf[t] = S^T[key tile t][q], 2 tiles x 12 ksteps, 2 acc chains each
    f32x16 sf[2];
#pragma unroll
    for (int t = 0; t < 2; t++) {
      if (c0 + t * 32 <= qmax) {
        f32x16 a0, a1;
#pragma unroll
        for (int r = 0; r < 16; r++) { a0[r] = 0.f; a1[r] = 0.f; }
#pragma unroll
        for (int kst = 0; kst < 12; kst++) {
          bf16x8 kfr = *reinterpret_cast<const bf16x8*>(
              Ks + (t * 32 + lo5) * 192 + (((kst * 2 + hi) ^ l7) * 8));
          if (kst & 1) a1 = mfma32(kfr, aq[kst], a1);
          else         a0 = mfma32(kfr, aq[kst], a0);
        }
        sf[t] = a0 + a1;
      } else {
#pragma unroll
        for (int r = 0; r < 16; r++) sf[t][r] = 0.f;
      }
    }

    // scale + causal mask + in-lane max (keys for this lane: t*32+(r&3)+8*(r>>2)+4*hi)
    float mx = -3e38f;
#pragma unroll
    for (int t = 0; t < 2; t++) {
#pragma unroll
      for (int r = 0; r < 16; r++) {
        int key = c0 + t * 32 + (r & 3) + 8 * (r >> 2) + 4 * hi;
        float v = sf[t][r] * scale;
        v = (key <= q) ? v : -1e30f;
        sf[t][r] = v;
        mx = fmaxf(mx, v);
      }
    }
    mx = fmaxf(mx, __shfl_xor(mx, 32, 64));  // combine complementary key halves
    float mnew = fmaxf(mrow, mx);
    float corr = __expf(mrow - mnew);
    mrow = mnew;
    float psum = 0.f;
#pragma unroll
    for (int t = 0; t < 2; t++)
#pragma unroll
      for (int r = 0; r < 16; r++) {
        float p = __expf(sf[t][r] - mnew);
        sf[t][r] = p;
        psum += p;
      }
    psum += __shfl_xor(psum, 32, 64);
    lrow = lrow * corr + psum;
#pragma unroll
    for (int dt = 0; dt < 4; dt++) Oacc[dt] *= corr;

    // P -> bf16 B-frags, in-register: 4 cvt_pk + 2 permlane32_swap per 16-key step
    bf16x8 pb[4];
#pragma unroll
    for (int ks = 0; ks < 4; ks++) {
      if (c0 + ks * 16 > qmax) continue;
      int t = ks >> 1, base = (ks & 1) * 8;
      unsigned Xa = cvtpk(sf[t][base + 0], sf[t][base + 1]);
      unsigned Xb = cvtpk(sf[t][base + 2], sf[t][base + 3]);
      unsigned Ya = cvtpk(sf[t][base + 4], sf[t][base + 5]);
      unsigned Yb = cvtpk(sf[t][base + 6], sf[t][base + 7]);
      plswap(Xa, Ya, hi != 0);
      plswap(Xb, Yb, hi != 0);
      union { unsigned u[4]; bf16x8 v; } pk_;
      pk_.u[0] = Xa; pk_.u[1] = Xb; pk_.u[2] = Ya; pk_.u[3] = Yb;
      pb[ks] = pk_.v;
    }

    // PV: O^T[d][q] += V x P, 4 d-tiles x 4 ksteps
#pragma unroll
    for (int ks = 0; ks < 4; ks++) {
      if (c0 + ks * 16 > qmax) continue;
#pragma unroll
      for (int dt = 0; dt < 4; dt++) {
        bf16x8 vfr = *reinterpret_cast<const bf16x8*>(
            Vs + (dt * 32 + lo5) * 64 + (((ks * 2 + hi) ^ l7) * 8));
        Oacc[dt] = mfma32(vfr, pb[ks], Oacc[dt]);
      }
    }
  }

  // epilogue: normalize (lane-local l), transpose via LDS, coalesced store
  __syncthreads();  // all PV done before smem reuse
  BF* Osh = (BF*)smem;  // [128 rows][136 elems] (pad 8 vs 128 to spread banks)
  float rinv = 1.0f / lrow;
  const int orow = w * 32 + lo5;
#pragma unroll
  for (int dt = 0; dt < 4; dt++) {
#pragma unroll
    for (int g = 0; g < 4; g++) {
      unsigned d0 = cvtpk(Oacc[dt][g * 4 + 0] * rinv, Oacc[dt][g * 4 + 1] * rinv);
      unsigned d1 = cvtpk(Oacc[dt][g * 4 + 2] * rinv, Oacc[dt][g * 4 + 3] * rinv);
      uint2 pr; pr.x = d0; pr.y = d1;
      *reinterpret_cast<uint2*>(Osh + orow * 136 + dt * 32 + g * 8 + hi * 4) = pr;
    }
  }
  __syncthreads();
  const int b = bh >> 4, h = bh & 15;
  const int cb = tid & 15, rb = tid >> 4;
#pragma unroll
  for (int rr = 0; rr < 8; rr++) {
    int row = rb + rr * 16;
    bf16x8 v = *reinterpret_cast<const bf16x8*>(Osh + row * 136 + cb * 8);
    *reinterpret_cast<bf16x8*>(o + ((size_t)(b * 2048 + q0 + row)) * 2048 + h * 128 + cb * 8) = v;
  }
}

extern "C" void kernel_launch(void* const* d_in, const int* in_sizes, int n_in,
                              void* d_out, int out_size, void* d_ws, size_t ws_size,
                              hipStream_t stream) {
  const float* hs   = (const float*)d_in[0];
  const float* wDKV = (const float*)d_in[2];
  const float* wUK  = (const float*)d_in[3];
  const float* wUV  = (const float*)d_in[4];
  const float* wDQ  = (const float*)d_in[5];
  const float* wUQ  = (const float*)d_in[6];
  const float* wQR  = (const float*)d_in[7];
  const float* wKR  = (const float*)d_in[8];
  const float* wO   = (const float*)d_in[9];
  float* out = (float*)d_out;

  char* ws = (char*)d_ws;
  size_t off = 0;
  auto alloc = [&](size_t bytes) -> char* {
    char* p = ws + off;
    off += (bytes + 255) & ~(size_t)255;
    return p;
  };
  BF* hsb   = (BF*)alloc((size_t)M_ * HID_ * 2);        // 4096x2048
  BF* tDKV  = (BF*)alloc((size_t)CKV_ * HID_ * 2);      // (512,2048)
  BF* tUK   = (BF*)alloc((size_t)(NH_*HD_) * CKV_ * 2); // (2048,512)
  BF* tUV   = (BF*)alloc((size_t)(NH_*HD_) * CKV_ * 2); // (2048,512)
  BF* tDQ   = (BF*)alloc((size_t)CQ_ * HID_ * 2);       // (1024,2048)
  BF* tUQ   = (BF*)alloc((size_t)(NH_*HD_) * CQ_ * 2);  // (2048,1024)
  BF* tQR   = (BF*)alloc((size_t)(NH_*RD_) * CQ_ * 2);  // (1024,1024)
  BF* tKR   = (BF*)alloc((size_t)128 * HID_ * 2);       // (128,2048) padded
  BF* tWO   = (BF*)alloc((size_t)HID_ * (NH_*HD_) * 2); // (2048,2048)
  BF* cKV   = (BF*)alloc((size_t)M_ * CKV_ * 2);
  BF* cQ    = (BF*)alloc((size_t)M_ * CQ_ * 2);
  BF* qbuf  = (BF*)alloc((size_t)B_ * NH_ * S_ * DQK_ * 2);
  BF* kbuf  = (BF*)alloc((size_t)B_ * NH_ * S_ * DQK_ * 2);
  BF* vTb   = (BF*)alloc((size_t)B_ * NH_ * HD_ * S_ * 2);
  BF* qRt   = (BF*)alloc((size_t)M_ * (NH_*RD_) * 2);
  BF* kRt   = (BF*)alloc((size_t)M_ * 128 * 2);
  BF* aout  = (BF*)alloc((size_t)M_ * (NH_*HD_) * 2);

  // 1. hidden -> bf16
  f2b_kern<<<(M_ * HID_ / 4 + 255) / 256, 256, 0, stream>>>(hs, hsb, M_ * HID_ / 4);

  // 2. weight transposes (fp32 (K,N) -> bf16 (Npad,K))
  dim3 tb(32, 8);
  wtrans<<<dim3(CKV_ / 32, HID_ / 32), tb, 0, stream>>>(wDKV, tDKV, HID_, CKV_, CKV_);
  wtrans<<<dim3((NH_*HD_) / 32, CKV_ / 32), tb, 0, stream>>>(wUK, tUK, CKV_, NH_*HD_, NH_*HD_);
  wtrans<<<dim3((NH_*HD_) / 32, CKV_ / 32), tb, 0, stream>>>(wUV, tUV, CKV_, NH_*HD_, NH_*HD_);
  wtrans<<<dim3(CQ_ / 32, HID_ / 32), tb, 0, stream>>>(wDQ, tDQ, HID_, CQ_, CQ_);
  wtrans<<<dim3((NH_*HD_) / 32, CQ_ / 32), tb, 0, stream>>>(wUQ, tUQ, CQ_, NH_*HD_, NH_*HD_);
  wtrans<<<dim3((NH_*RD_) / 32, CQ_ / 32), tb, 0, stream>>>(wQR, tQR, CQ_, NH_*RD_, NH_*RD_);
  wtrans<<<dim3(128 / 32, HID_ / 32), tb, 0, stream>>>(wKR, tKR, HID_, RD_, 128);
  wtrans<<<dim3((NH_*HD_) / 32, HID_ / 32), tb, 0, stream>>>(wO, tWO, HID_, NH_*HD_, NH_*HD_);

  // 3. projections
  gemm_bt<0><<<dim3(CKV_ / 128, M_ / 128), 256, 0, stream>>>(hsb, tDKV, cKV, M_, CKV_, HID_);
  gemm_bt<0><<<dim3(CQ_ / 128, M_ / 128), 256, 0, stream>>>(hsb, tDQ, cQ, M_, CQ_, HID_);
  gemm_bt<1><<<dim3((NH_*HD_) / 128, M_ / 128), 256, 0, stream>>>(cKV, tUK, kbuf, M_, NH_*HD_, CKV_);
  gemm_bt<2><<<dim3((NH_*HD_) / 128, M_ / 128), 256, 0, stream>>>(cKV, tUV, vTb, M_, NH_*HD_, CKV_);
  gemm_bt<1><<<dim3((NH_*HD_) / 128, M_ / 128), 256, 0, stream>>>(cQ, tUQ, qbuf, M_, NH_*HD_, CQ_);
  gemm_bt<0><<<dim3((NH_*RD_) / 128, M_ / 128), 256, 0, stream>>>(cQ, tQR, qRt, M_, NH_*RD_, CQ_);
  gemm_bt<0><<<dim3(128 / 128, M_ / 128), 256, 0, stream>>>(hsb, tKR, kRt, M_, 128, HID_);

  // 4. RoPE
  rope_q<<<(M_ * NH_ * RD_) / 256, 256, 0, stream>>>(qRt, qbuf);
  rope_k<<<(M_ * RD_) / 256, 256, 0, stream>>>(kRt, kbuf);

  // 5. attention (QBLK=128, KVBLK=64, 32x32 MFMA, in-register P)
  attn_kern<<<dim3(S_ / 128, B_ * NH_), 256, 0, stream>>>(qbuf, kbuf, vTb, aout);

  // 6. output projection (fp32 out)
  gemm_bt<3><<<dim3((NH_*HD_) / 128, M_ / 128), 256, 0, stream>>>(aout, tWO, out, M_, NH_*HD_, HID_);
}

// Round 8
// 392.028 us; speedup vs baseline: 1.5493x; 1.1655x over previous
//
#include <hip/hip_runtime.h>
#include <hip/hip_bf16.h>

typedef __bf16 bf16x8 __attribute__((ext_vector_type(8)));
typedef float f32x4 __attribute__((ext_vector_type(4)));
typedef float f32x16 __attribute__((ext_vector_type(16)));
using BF = __hip_bfloat16;

// Problem constants
constexpr int B_   = 2;
constexpr int S_   = 2048;
constexpr int NH_  = 16;
constexpr int HD_  = 128;
constexpr int HID_ = 2048;
constexpr int CKV_ = 512;
constexpr int CQ_  = 1024;
constexpr int RD_  = 64;
constexpr int M_   = B_ * S_;     // 4096 tokens
constexpr int DQK_ = HD_ + RD_;   // 192

__device__ __forceinline__ f32x4 mfma16(bf16x8 a, bf16x8 b, f32x4 c) {
  return __builtin_amdgcn_mfma_f32_16x16x32_bf16(a, b, c, 0, 0, 0);
}
__device__ __forceinline__ f32x16 mfma32(bf16x8 a, bf16x8 b, f32x16 c) {
  return __builtin_amdgcn_mfma_f32_32x32x16_bf16(a, b, c, 0, 0, 0);
}
__device__ __forceinline__ unsigned cvtpk(float a, float b) {
  unsigned r;
  asm("v_cvt_pk_bf16_f32 %0, %1, %2" : "=v"(r) : "v"(a), "v"(b));
  return r;
}
// async global->LDS, 16B per lane; dest must be linear in lane order (G21)
__device__ __forceinline__ void gload16(const void* g, void* lds) {
  __builtin_amdgcn_global_load_lds((const __attribute__((address_space(1))) void*)g,
                                   (__attribute__((address_space(3))) void*)lds,
                                   16, 0, 0);
}
// (x,y) -> x' = low-half frag, y' = high-half frag
__device__ __forceinline__ void plswap(unsigned& x, unsigned& y, bool hi) {
#if __has_builtin(__builtin_amdgcn_permlane32_swap)
  typedef unsigned u32x2 __attribute__((ext_vector_type(2)));
  u32x2 r = __builtin_amdgcn_permlane32_swap(x, y, false, false);
  x = r[0];
  y = r[1];
#else
  unsigned sx = (unsigned)__shfl_xor((int)x, 32, 64);
  unsigned sy = (unsigned)__shfl_xor((int)y, 32, 64);
  unsigned nx = hi ? sy : x;
  unsigned ny = hi ? y : sx;
  x = nx;
  y = ny;
#endif
}

// ---------------- fp32 -> bf16 convert (vectorized) ----------------
__global__ __launch_bounds__(256) void f2b_kern(const float* __restrict__ in,
                                                BF* __restrict__ out, int n4) {
  int i = blockIdx.x * 256 + threadIdx.x;
  if (i >= n4) return;
  float4 v = reinterpret_cast<const float4*>(in)[i];
  BF o[4] = {__float2bfloat16(v.x), __float2bfloat16(v.y),
             __float2bfloat16(v.z), __float2bfloat16(v.w)};
  reinterpret_cast<uint2*>(out)[i] = *reinterpret_cast<uint2*>(o);
}

// ------------- tiled transpose fp32 (K,N) -> bf16 (Npad,K), zero-pad n>=N -------------
__global__ __launch_bounds__(256) void wtrans(const float* __restrict__ in,
                                              BF* __restrict__ out,
                                              int K, int N, int Npad) {
  __shared__ float t[32][33];
  int n0 = blockIdx.x * 32, k0 = blockIdx.y * 32;
  int tx = threadIdx.x, ty = threadIdx.y;
#pragma unroll
  for (int j = 0; j < 4; j++) {
    int k = k0 + ty + j * 8, n = n0 + tx;
    t[ty + j * 8][tx] = (n < N) ? in[(size_t)k * N + n] : 0.f;
  }
  __syncthreads();
#pragma unroll
  for (int j = 0; j < 4; j++) {
    int n = n0 + ty + j * 8, k = k0 + tx;
    out[(size_t)n * K + k] = __float2bfloat16(t[tx][ty + j * 8]);
  }
}

// ---------------- fused GEMM: C = A(M,K) x Bt(N,K)^T, bf16 in, fp32 acc -------------
// 128x128 tile, BK=32, global_load_lds(16B) staging, 4 waves (2x2), 64x64/wave.
// F=1: col<512 -> C0=cKV[.,512]; col<1536 -> C1=cQ[.,1024]; else C2=kRt[.,128]
// F=2: col<2048 -> C0=kbuf head-scatter; else C1=vTb v^T scatter
// F=3: col<2048 -> C0=qbuf head-scatter; else C1=qRt[.,1024]
// F=4: C0=out fp32 [.,2048]
template <int F>
__global__ __launch_bounds__(256) void gemm_f(const BF* __restrict__ A,
                                              const BF* __restrict__ Bt,
                                              void* __restrict__ C0,
                                              void* __restrict__ C1,
                                              void* __restrict__ C2,
                                              int M, int N, int K) {
  __shared__ BF As[128][32];
  __shared__ BF Bs[128][32];
  const int tid = threadIdx.x;
  const int w = tid >> 6, l = tid & 63;
  const int lr = l & 15, lg = l >> 4;
  const int wr = w >> 1, wc = w & 1;
  const int m0 = blockIdx.y * 128, n0 = blockIdx.x * 128;

  f32x4 acc[4][4];
#pragma unroll
  for (int m = 0; m < 4; m++)
#pragma unroll
    for (int n = 0; n < 4; n++) acc[m][n] = (f32x4){0.f, 0.f, 0.f, 0.f};

  for (int k0 = 0; k0 < K; k0 += 32) {
    __syncthreads();
#pragma unroll
    for (int j = 0; j < 2; j++) {
      int idx = tid + j * 256;
      int row = idx >> 2, seg = idx & 3;
      gload16(A + (size_t)(m0 + row) * K + k0 + seg * 8, &As[0][0] + idx * 8);
      gload16(Bt + (size_t)(n0 + row) * K + k0 + seg * 8, &Bs[0][0] + idx * 8);
    }
    __syncthreads();
    bf16x8 af[4], bfr[4];
#pragma unroll
    for (int m = 0; m < 4; m++)
      af[m] = *reinterpret_cast<const bf16x8*>(&As[wr * 64 + m * 16 + lr][lg * 8]);
#pragma unroll
    for (int n = 0; n < 4; n++)
      bfr[n] = *reinterpret_cast<const bf16x8*>(&Bs[wc * 64 + n * 16 + lr][lg * 8]);
#pragma unroll
    for (int m = 0; m < 4; m++)
#pragma unroll
      for (int n = 0; n < 4; n++) acc[m][n] = mfma16(af[m], bfr[n], acc[m][n]);
  }

  // epilogue: C/D layout col = lane&15, row = (lane>>4)*4 + j  (m89-verified)
#pragma unroll
  for (int m = 0; m < 4; m++) {
#pragma unroll
    for (int n = 0; n < 4; n++) {
#pragma unroll
      for (int j = 0; j < 4; j++) {
        int row = m0 + wr * 64 + m * 16 + lg * 4 + j;
        int col = n0 + wc * 64 + n * 16 + lr;
        float v = acc[m][n][j];
        if constexpr (F == 1) {
          if (col < 512)
            ((BF*)C0)[(size_t)row * 512 + col] = __float2bfloat16(v);
          else if (col < 1536)
            ((BF*)C1)[(size_t)row * 1024 + (col - 512)] = __float2bfloat16(v);
          else
            ((BF*)C2)[(size_t)row * 128 + (col - 1536)] = __float2bfloat16(v);
        } else if constexpr (F == 2) {
          int b = row >> 11, s = row & 2047;
          if (col < 2048) {
            int h = col >> 7, d = col & 127;
            ((BF*)C0)[((size_t)(b * 16 + h) * 2048 + s) * 192 + d] = __float2bfloat16(v);
          } else {
            int c2 = col - 2048, h = c2 >> 7, d = c2 & 127;
            ((BF*)C1)[((size_t)(b * 16 + h) * 128 + d) * 2048 + s] = __float2bfloat16(v);
          }
        } else if constexpr (F == 3) {
          if (col < 2048) {
            int b = row >> 11, s = row & 2047, h = col >> 7, d = col & 127;
            ((BF*)C0)[((size_t)(b * 16 + h) * 2048 + s) * 192 + d] = __float2bfloat16(v);
          } else {
            ((BF*)C1)[(size_t)row * 1024 + (col - 2048)] = __float2bfloat16(v);
          }
        } else {
          ((float*)C0)[(size_t)row * 2048 + col] = v;
        }
      }
    }
  }
}

// ---------------- RoPE ----------------
__global__ __launch_bounds__(256) void rope_q(const BF* __restrict__ qr, BF* __restrict__ qb) {
  int idx = blockIdx.x * 256 + threadIdx.x;  // 4096*16*64
  int d = idx & 63, h = (idx >> 6) & 15, m = idx >> 10;
  int s = m & 2047, b = m >> 11;
  float x = __bfloat162float(qr[(size_t)(m << 10) + (h << 6) + d]);
  float other = __bfloat162float(qr[(size_t)(m << 10) + (h << 6) + (d ^ 32)]);
  float rot = (d < 32) ? -other : other;
  int di = d & 31;
  float arg = (float)s * powf(10000.f, -(float)di / 32.0f);
  float c = cosf(arg), sn = sinf(arg);
  qb[((size_t)(b * 16 + h) * 2048 + s) * 192 + 128 + d] = __float2bfloat16(x * c + rot * sn);
}

__global__ __launch_bounds__(256) void rope_k(const BF* __restrict__ kr, BF* __restrict__ kb) {
  int idx = blockIdx.x * 256 + threadIdx.x;  // 4096*64
  int d = idx & 63, m = idx >> 6;
  int s = m & 2047, b = m >> 11;
  float x = __bfloat162float(kr[(size_t)m * 128 + d]);
  float other = __bfloat162float(kr[(size_t)m * 128 + (d ^ 32)]);
  float rot = (d < 32) ? -other : other;
  int di = d & 31;
  float arg = (float)s * powf(10000.f, -(float)di / 32.0f);
  float val = x * cosf(arg) + rot * sinf(arg);
  BF v = __float2bfloat16(val);
#pragma unroll
  for (int h = 0; h < 16; h++)
    kb[((size_t)(b * 16 + h) * 2048 + s) * 192 + 128 + d] = v;
}

// ---------------- flash attention v5: 2-phase pipelined K/V staging ----------------
// QBLK=128 (4 waves x 32 q), KVBLK=64, double-buffered LDS (80 KB).
// Per chunk: {STAGE(next buf) -> compute(cur) -> __syncthreads}: the compiler's
// vmcnt(0) drain before s_barrier lands AFTER compute, hiding stage latency (T3-min).
__global__ __launch_bounds__(256, 2) void attn_kern(const BF* __restrict__ qb,
                                                    const BF* __restrict__ kb,
                                                    const BF* __restrict__ vT,
                                                    BF* __restrict__ o) {
  const int bh = blockIdx.y;
  const int q0 = ((int)gridDim.x - 1 - (int)blockIdx.x) * 128;  // longest first
  const int tid = threadIdx.x;
  const int w = tid >> 6, l = tid & 63;
  const int lo5 = l & 31;
  const int hi = l >> 5;
  const int l7 = l & 7;

  // buffer b: Ks (64x192x2B = 24576) at b*40960, Vs (128x64x2B) at b*40960+24576
  __shared__ __align__(16) char smem[81920];

  const int q = q0 + w * 32 + lo5;   // this lane's q-row
  const int qmax = q0 + w * 32 + 31; // wave-uniform

  // Q fragments: B-operand, 12 k-steps of 16 (D=192)
  bf16x8 aq[12];
  {
    const BF* qrow = qb + ((size_t)bh * 2048 + q) * 192;
#pragma unroll
    for (int kst = 0; kst < 12; kst++)
      aq[kst] = *reinterpret_cast<const bf16x8*>(qrow + kst * 16 + hi * 8);
  }

  f32x16 Oacc[4];
#pragma unroll
  for (int dt = 0; dt < 4; dt++)
#pragma unroll
    for (int r = 0; r < 16; r++) Oacc[dt][r] = 0.f;
  float mrow = -3e38f, lrow = 0.f;

  const float scale = 0.07216878364870323f;  // 1/sqrt(192)
  const int nch = (q0 + 128) >> 6;

  auto STAGE = [&](int buf, int ch) {
    const int cc = ch << 6;
    BF* Ks = (BF*)(smem + buf * 40960);
    BF* Vs = (BF*)(smem + buf * 40960 + 24576);
#pragma unroll
    for (int j2 = 0; j2 < 6; j2++) {
      int D = tid + j2 * 256;
      int row = D / 24, sp = D % 24;
      int sl = sp ^ (row & 7);
      gload16(kb + ((size_t)bh * 2048 + cc + row) * 192 + sl * 8, Ks + D * 8);
    }
#pragma unroll
    for (int j2 = 0; j2 < 4; j2++) {
      int D = tid + j2 * 256;
      int row = D >> 3, sp = D & 7;
      int sl = sp ^ (row & 7);
      gload16(vT + ((size_t)bh * 128 + row) * 2048 + cc + sl * 8, Vs + D * 8);
    }
  };

  STAGE(0, 0);
  __syncthreads();  // drains vmcnt(0): chunk 0 staged

  for (int ch = 0; ch < nch; ch++) {
    const int c0 = ch << 6;
    const int cur = ch & 1;
    if (ch + 1 < nch) STAGE(cur ^ 1, ch + 1);  // issue next-chunk loads FIRST
    __builtin_amdgcn_sched_barrier(0);         // pin issue before compute
    BF* Ks = (BF*)(smem + cur * 40960);
    BF* Vs = (BF*)(smem + cur * 40960 + 24576);

    // QK^T (swapped): sf[t] = S^T[key tile t][q], 2 tiles x 12 ksteps
    f32x16 sf[2];
#pragma unroll
    for (int t = 0; t < 2; t++) {
      if (c0 + t * 32 <= qmax) {
        f32x16 a0, a1;
#pragma unroll
        for (int r = 0; r < 16; r++) { a0[r] = 0.f; a1[r] = 0.f; }
#pragma unroll
        for (int kst = 0; kst < 12; kst++) {
          bf16x8 kfr = *reinterpret_cast<const bf16x8*>(
              Ks + (t * 32 + lo5) * 192 + (((kst * 2 + hi) ^ l7) * 8));
          if (kst & 1) a1 = mfma32(kfr, aq[kst], a1);
          else         a0 = mfma32(kfr, aq[kst], a0);
        }
        sf[t] = a0 + a1;
      } else {
#pragma unroll
        for (int r = 0; r < 16; r++) sf[t][r] = 0.f;
      }
    }

    // scale + causal mask + in-lane max (keys: t*32+(r&3)+8*(r>>2)+4*hi)
    float mx = -3e38f;
#pragma unroll
    for (int t = 0; t < 2; t++) {
#pragma unroll
      for (int r = 0; r < 16; r++) {
        int key = c0 + t * 32 + (r & 3) + 8 * (r >> 2) + 4 * hi;
        float v = sf[t][r] * scale;
        v = (key <= q) ? v : -1e30f;
        sf[t][r] = v;
        mx = fmaxf(mx, v);
      }
    }
    mx = fmaxf(mx, __shfl_xor(mx, 32, 64));  // combine complementary key halves
    float mnew = fmaxf(mrow, mx);
    float corr = __expf(mrow - mnew);
    mrow = mnew;
    float psum = 0.f;
#pragma unroll
    for (int t = 0; t < 2; t++)
#pragma unroll
      for (int r = 0; r < 16; r++) {
        float p = __expf(sf[t][r] - mnew);
        sf[t][r] = p;
        psum += p;
      }
    psum += __shfl_xor(psum, 32, 64);
    lrow = lrow * corr + psum;
#pragma unroll
    for (int dt = 0; dt < 4; dt++) Oacc[dt] *= corr;

    // P -> bf16 B-frags, in-register: cvt_pk + permlane32_swap
    bf16x8 pb[4];
#pragma unroll
    for (int ks = 0; ks < 4; ks++) {
      if (c0 + ks * 16 > qmax) continue;
      int t = ks >> 1, base = (ks & 1) * 8;
      unsigned Xa = cvtpk(sf[t][base + 0], sf[t][base + 1]);
      unsigned Xb = cvtpk(sf[t][base + 2], sf[t][base + 3]);
      unsigned Ya = cvtpk(sf[t][base + 4], sf[t][base + 5]);
      unsigned Yb = cvtpk(sf[t][base + 6], sf[t][base + 7]);
      plswap(Xa, Ya, hi != 0);
      plswap(Xb, Yb, hi != 0);
      union { unsigned u[4]; bf16x8 v; } pk_;
      pk_.u[0] = Xa; pk_.u[1] = Xb; pk_.u[2] = Ya; pk_.u[3] = Yb;
      pb[ks] = pk_.v;
    }

    // PV: O^T[d][q] += V x P, 4 d-tiles x 4 ksteps
#pragma unroll
    for (int ks = 0; ks < 4; ks++) {
      if (c0 + ks * 16 > qmax) continue;
#pragma unroll
      for (int dt = 0; dt < 4; dt++) {
        bf16x8 vfr = *reinterpret_cast<const bf16x8*>(
            Vs + (dt * 32 + lo5) * 64 + (((ks * 2 + hi) ^ l7) * 8));
        Oacc[dt] = mfma32(vfr, pb[ks], Oacc[dt]);
      }
    }
    __syncthreads();  // next buffer staged + all waves done reading cur
  }

  // epilogue: normalize (lane-local l), transpose via LDS, coalesced store
  BF* Osh = (BF*)smem;  // [128 rows][136 elems]
  float rinv = 1.0f / lrow;
  const int orow = w * 32 + lo5;
#pragma unroll
  for (int dt = 0; dt < 4; dt++) {
#pragma unroll
    for (int g = 0; g < 4; g++) {
      unsigned d0 = cvtpk(Oacc[dt][g * 4 + 0] * rinv, Oacc[dt][g * 4 + 1] * rinv);
      unsigned d1 = cvtpk(Oacc[dt][g * 4 + 2] * rinv, Oacc[dt][g * 4 + 3] * rinv);
      uint2 pr; pr.x = d0; pr.y = d1;
      *reinterpret_cast<uint2*>(Osh + orow * 136 + dt * 32 + g * 8 + hi * 4) = pr;
    }
  }
  __syncthreads();
  const int b = bh >> 4, h = bh & 15;
  const int cb = tid & 15, rb = tid >> 4;
#pragma unroll
  for (int rr = 0; rr < 8; rr++) {
    int row = rb + rr * 16;
    bf16x8 v = *reinterpret_cast<const bf16x8*>(Osh + row * 136 + cb * 8);
    *reinterpret_cast<bf16x8*>(o + ((size_t)(b * 2048 + q0 + row)) * 2048 + h * 128 + cb * 8) = v;
  }
}

extern "C" void kernel_launch(void* const* d_in, const int* in_sizes, int n_in,
                              void* d_out, int out_size, void* d_ws, size_t ws_size,
                              hipStream_t stream) {
  const float* hs   = (const float*)d_in[0];
  const float* wDKV = (const float*)d_in[2];
  const float* wUK  = (const float*)d_in[3];
  const float* wUV  = (const float*)d_in[4];
  const float* wDQ  = (const float*)d_in[5];
  const float* wUQ  = (const float*)d_in[6];
  const float* wQR  = (const float*)d_in[7];
  const float* wKR  = (const float*)d_in[8];
  const float* wO   = (const float*)d_in[9];
  float* out = (float*)d_out;

  char* ws = (char*)d_ws;
  size_t off = 0;
  auto alloc = [&](size_t bytes) -> char* {
    char* p = ws + off;
    off += (bytes + 255) & ~(size_t)255;
    return p;
  };
  BF* hsb   = (BF*)alloc((size_t)M_ * HID_ * 2);          // 4096x2048
  BF* tCat1 = (BF*)alloc((size_t)1664 * HID_ * 2);        // [DKV;DQ;KRpad] x 2048
  BF* tCat2 = (BF*)alloc((size_t)4096 * CKV_ * 2);        // [UK;UV] x 512
  BF* tCat3 = (BF*)alloc((size_t)3072 * CQ_ * 2);         // [UQ;QR] x 1024
  BF* tWO   = (BF*)alloc((size_t)HID_ * (NH_*HD_) * 2);   // (2048,2048)
  BF* cKV   = (BF*)alloc((size_t)M_ * CKV_ * 2);
  BF* cQ    = (BF*)alloc((size_t)M_ * CQ_ * 2);
  BF* qbuf  = (BF*)alloc((size_t)B_ * NH_ * S_ * DQK_ * 2);
  BF* kbuf  = (BF*)alloc((size_t)B_ * NH_ * S_ * DQK_ * 2);
  BF* vTb   = (BF*)alloc((size_t)B_ * NH_ * HD_ * S_ * 2);
  BF* qRt   = (BF*)alloc((size_t)M_ * (NH_*RD_) * 2);
  BF* kRt   = (BF*)alloc((size_t)M_ * 128 * 2);
  BF* aout  = (BF*)alloc((size_t)M_ * (NH_*HD_) * 2);

  // 1. hidden -> bf16
  f2b_kern<<<(M_ * HID_ / 4 + 255) / 256, 256, 0, stream>>>(hs, hsb, M_ * HID_ / 4);

  // 2. weight transposes into concatenated B^T panels
  dim3 tb(32, 8);
  wtrans<<<dim3(512 / 32, HID_ / 32), tb, 0, stream>>>(wDKV, tCat1, HID_, 512, 512);
  wtrans<<<dim3(1024 / 32, HID_ / 32), tb, 0, stream>>>(wDQ, tCat1 + (size_t)512 * HID_, HID_, 1024, 1024);
  wtrans<<<dim3(128 / 32, HID_ / 32), tb, 0, stream>>>(wKR, tCat1 + (size_t)1536 * HID_, HID_, 64, 128);
  wtrans<<<dim3(2048 / 32, CKV_ / 32), tb, 0, stream>>>(wUK, tCat2, CKV_, 2048, 2048);
  wtrans<<<dim3(2048 / 32, CKV_ / 32), tb, 0, stream>>>(wUV, tCat2 + (size_t)2048 * CKV_, CKV_, 2048, 2048);
  wtrans<<<dim3(2048 / 32, CQ_ / 32), tb, 0, stream>>>(wUQ, tCat3, CQ_, 2048, 2048);
  wtrans<<<dim3(1024 / 32, CQ_ / 32), tb, 0, stream>>>(wQR, tCat3 + (size_t)2048 * CQ_, CQ_, 1024, 1024);
  wtrans<<<dim3(2048 / 32, HID_ / 32), tb, 0, stream>>>(wO, tWO, HID_, 2048, 2048);

  // 3. fused projections
  gemm_f<1><<<dim3(1664 / 128, M_ / 128), 256, 0, stream>>>(hsb, tCat1, cKV, cQ, kRt, M_, 1664, HID_);
  gemm_f<3><<<dim3(3072 / 128, M_ / 128), 256, 0, stream>>>(cQ, tCat3, qbuf, qRt, nullptr, M_, 3072, CQ_);
  gemm_f<2><<<dim3(4096 / 128, M_ / 128), 256, 0, stream>>>(cKV, tCat2, kbuf, vTb, nullptr, M_, 4096, CKV_);

  // 4. RoPE
  rope_q<<<(M_ * NH_ * RD_) / 256, 256, 0, stream>>>(qRt, qbuf);
  rope_k<<<(M_ * RD_) / 256, 256, 0, stream>>>(kRt, kbuf);

  // 5. attention (QBLK=128, KVBLK=64, 32x32 MFMA, in-register P, 2-phase pipeline)
  attn_kern<<<dim3(S_ / 128, B_ * NH_), 256, 0, stream>>>(qbuf, kbuf, vTb, aout);

  // 6. output projection (fp32 out)
  gemm_f<4><<<dim3(2048 / 128, M_ / 128), 256, 0, stream>>>(aout, tWO, out, nullptr, nullptr, M_, 2048, HID_);
}

// Round 9
// 346.794 us; speedup vs baseline: 1.7514x; 1.1304x over previous
//
#include <hip/hip_runtime.h>
#include <hip/hip_bf16.h>

typedef __bf16 bf16x8 __attribute__((ext_vector_type(8)));
typedef float f32x4 __attribute__((ext_vector_type(4)));
typedef float f32x16 __attribute__((ext_vector_type(16)));
using BF = __hip_bfloat16;

// Problem constants
constexpr int B_   = 2;
constexpr int S_   = 2048;
constexpr int NH_  = 16;
constexpr int HD_  = 128;
constexpr int HID_ = 2048;
constexpr int CKV_ = 512;
constexpr int CQ_  = 1024;
constexpr int RD_  = 64;
constexpr int M_   = B_ * S_;     // 4096 tokens
constexpr int DQK_ = HD_ + RD_;   // 192

__device__ __forceinline__ f32x4 mfma16(bf16x8 a, bf16x8 b, f32x4 c) {
  return __builtin_amdgcn_mfma_f32_16x16x32_bf16(a, b, c, 0, 0, 0);
}
__device__ __forceinline__ f32x16 mfma32(bf16x8 a, bf16x8 b, f32x16 c) {
  return __builtin_amdgcn_mfma_f32_32x32x16_bf16(a, b, c, 0, 0, 0);
}
__device__ __forceinline__ unsigned cvtpk(float a, float b) {
  unsigned r;
  asm("v_cvt_pk_bf16_f32 %0, %1, %2" : "=v"(r) : "v"(a), "v"(b));
  return r;
}
// async global->LDS, 16B per lane; dest must be linear in lane order (G21)
__device__ __forceinline__ void gload16(const void* g, void* lds) {
  __builtin_amdgcn_global_load_lds((const __attribute__((address_space(1))) void*)g,
                                   (__attribute__((address_space(3))) void*)lds,
                                   16, 0, 0);
}
// (x,y) -> x' = low-half frag, y' = high-half frag
__device__ __forceinline__ void plswap(unsigned& x, unsigned& y, bool hi) {
#if __has_builtin(__builtin_amdgcn_permlane32_swap)
  typedef unsigned u32x2 __attribute__((ext_vector_type(2)));
  u32x2 r = __builtin_amdgcn_permlane32_swap(x, y, false, false);
  x = r[0];
  y = r[1];
#else
  unsigned sx = (unsigned)__shfl_xor((int)x, 32, 64);
  unsigned sy = (unsigned)__shfl_xor((int)y, 32, 64);
  unsigned nx = hi ? sy : x;
  unsigned ny = hi ? y : sx;
  x = nx;
  y = ny;
#endif
}

// ---------------- fp32 -> bf16 convert (vectorized) ----------------
__global__ __launch_bounds__(256) void f2b_kern(const float* __restrict__ in,
                                                BF* __restrict__ out, int n4) {
  int i = blockIdx.x * 256 + threadIdx.x;
  if (i >= n4) return;
  float4 v = reinterpret_cast<const float4*>(in)[i];
  BF o[4] = {__float2bfloat16(v.x), __float2bfloat16(v.y),
             __float2bfloat16(v.z), __float2bfloat16(v.w)};
  reinterpret_cast<uint2*>(out)[i] = *reinterpret_cast<uint2*>(o);
}

// ------------- tiled transpose fp32 (K,N) -> bf16 (Npad,K), zero-pad n>=N -------------
__global__ __launch_bounds__(256) void wtrans(const float* __restrict__ in,
                                              BF* __restrict__ out,
                                              int K, int N, int Npad) {
  __shared__ float t[32][33];
  int n0 = blockIdx.x * 32, k0 = blockIdx.y * 32;
  int tx = threadIdx.x, ty = threadIdx.y;
#pragma unroll
  for (int j = 0; j < 4; j++) {
    int k = k0 + ty + j * 8, n = n0 + tx;
    t[ty + j * 8][tx] = (n < N) ? in[(size_t)k * N + n] : 0.f;
  }
  __syncthreads();
#pragma unroll
  for (int j = 0; j < 4; j++) {
    int n = n0 + ty + j * 8, k = k0 + tx;
    out[(size_t)n * K + k] = __float2bfloat16(t[tx][ty + j * 8]);
  }
}

// ---------------- fused GEMM: C = A(M,K) x Bt(N,K)^T, bf16 in, fp32 acc -------------
// 128x128 tile, BK=32, global_load_lds(16B) staging, XCD-aware block swizzle (T1).
// F=1: col<512 -> C0=cKV; col<1536 -> C1=cQ; else C2=kRt
// F=2: col<2048 -> C0=kbuf head-scatter; else C1=vTb v^T scatter
// F=3: col<2048 -> C0=qbuf head-scatter; else C1=qRt
// F=4: C0=out fp32
template <int F>
__global__ __launch_bounds__(256) void gemm_f(const BF* __restrict__ A,
                                              const BF* __restrict__ Bt,
                                              void* __restrict__ C0,
                                              void* __restrict__ C1,
                                              void* __restrict__ C2,
                                              int M, int N, int K) {
  __shared__ BF As[128][32];
  __shared__ BF Bs[128][32];
  const int tid = threadIdx.x;
  const int w = tid >> 6, l = tid & 63;
  const int lr = l & 15, lg = l >> 4;
  const int wr = w >> 1, wc = w & 1;
  // XCD swizzle: dispatch slot f -> work id (f%8)*(n/8)+f/8 (grids are %8==0)
  const int gx = gridDim.x;
  const int nwg = gx * gridDim.y;
  const int f = blockIdx.y * gx + blockIdx.x;
  const int swz = (f & 7) * (nwg >> 3) + (f >> 3);
  const int m0 = (swz / gx) * 128, n0 = (swz % gx) * 128;

  f32x4 acc[4][4];
#pragma unroll
  for (int m = 0; m < 4; m++)
#pragma unroll
    for (int n = 0; n < 4; n++) acc[m][n] = (f32x4){0.f, 0.f, 0.f, 0.f};

  for (int k0 = 0; k0 < K; k0 += 32) {
    __syncthreads();
#pragma unroll
    for (int j = 0; j < 2; j++) {
      int idx = tid + j * 256;
      int row = idx >> 2, seg = idx & 3;
      gload16(A + (size_t)(m0 + row) * K + k0 + seg * 8, &As[0][0] + idx * 8);
      gload16(Bt + (size_t)(n0 + row) * K + k0 + seg * 8, &Bs[0][0] + idx * 8);
    }
    __syncthreads();
    bf16x8 af[4], bfr[4];
#pragma unroll
    for (int m = 0; m < 4; m++)
      af[m] = *reinterpret_cast<const bf16x8*>(&As[wr * 64 + m * 16 + lr][lg * 8]);
#pragma unroll
    for (int n = 0; n < 4; n++)
      bfr[n] = *reinterpret_cast<const bf16x8*>(&Bs[wc * 64 + n * 16 + lr][lg * 8]);
#pragma unroll
    for (int m = 0; m < 4; m++)
#pragma unroll
      for (int n = 0; n < 4; n++) acc[m][n] = mfma16(af[m], bfr[n], acc[m][n]);
  }

  // epilogue: C/D layout col = lane&15, row = (lane>>4)*4 + j  (m89-verified)
#pragma unroll
  for (int m = 0; m < 4; m++) {
#pragma unroll
    for (int n = 0; n < 4; n++) {
#pragma unroll
      for (int j = 0; j < 4; j++) {
        int row = m0 + wr * 64 + m * 16 + lg * 4 + j;
        int col = n0 + wc * 64 + n * 16 + lr;
        float v = acc[m][n][j];
        if constexpr (F == 1) {
          if (col < 512)
            ((BF*)C0)[(size_t)row * 512 + col] = __float2bfloat16(v);
          else if (col < 1536)
            ((BF*)C1)[(size_t)row * 1024 + (col - 512)] = __float2bfloat16(v);
          else
            ((BF*)C2)[(size_t)row * 128 + (col - 1536)] = __float2bfloat16(v);
        } else if constexpr (F == 2) {
          int b = row >> 11, s = row & 2047;
          if (col < 2048) {
            int h = col >> 7, d = col & 127;
            ((BF*)C0)[((size_t)(b * 16 + h) * 2048 + s) * 192 + d] = __float2bfloat16(v);
          } else {
            int c2 = col - 2048, h = c2 >> 7, d = c2 & 127;
            ((BF*)C1)[((size_t)(b * 16 + h) * 128 + d) * 2048 + s] = __float2bfloat16(v);
          }
        } else if constexpr (F == 3) {
          if (col < 2048) {
            int b = row >> 11, s = row & 2047, h = col >> 7, d = col & 127;
            ((BF*)C0)[((size_t)(b * 16 + h) * 2048 + s) * 192 + d] = __float2bfloat16(v);
          } else {
            ((BF*)C1)[(size_t)row * 1024 + (col - 2048)] = __float2bfloat16(v);
          }
        } else {
          ((float*)C0)[(size_t)row * 2048 + col] = v;
        }
      }
    }
  }
}

// ---------------- RoPE ----------------
__global__ __launch_bounds__(256) void rope_q(const BF* __restrict__ qr, BF* __restrict__ qb) {
  int idx = blockIdx.x * 256 + threadIdx.x;  // 4096*16*64
  int d = idx & 63, h = (idx >> 6) & 15, m = idx >> 10;
  int s = m & 2047, b = m >> 11;
  float x = __bfloat162float(qr[(size_t)(m << 10) + (h << 6) + d]);
  float other = __bfloat162float(qr[(size_t)(m << 10) + (h << 6) + (d ^ 32)]);
  float rot = (d < 32) ? -other : other;
  int di = d & 31;
  float arg = (float)s * powf(10000.f, -(float)di / 32.0f);
  float c = cosf(arg), sn = sinf(arg);
  qb[((size_t)(b * 16 + h) * 2048 + s) * 192 + 128 + d] = __float2bfloat16(x * c + rot * sn);
}

__global__ __launch_bounds__(256) void rope_k(const BF* __restrict__ kr, BF* __restrict__ kb) {
  int idx = blockIdx.x * 256 + threadIdx.x;  // 4096*64
  int d = idx & 63, m = idx >> 6;
  int s = m & 2047, b = m >> 11;
  float x = __bfloat162float(kr[(size_t)m * 128 + d]);
  float other = __bfloat162float(kr[(size_t)m * 128 + (d ^ 32)]);
  float rot = (d < 32) ? -other : other;
  int di = d & 31;
  float arg = (float)s * powf(10000.f, -(float)di / 32.0f);
  float val = x * cosf(arg) + rot * sinf(arg);
  BF v = __float2bfloat16(val);
#pragma unroll
  for (int h = 0; h < 16; h++)
    kb[((size_t)(b * 16 + h) * 2048 + s) * 192 + 128 + d] = v;
}

// ---------------- flash attention v6: complementary pairing + setprio ----------------
// QBLK=128 (4 waves x 32 q), KVBLK=64, dbuf LDS (80 KB, 2 blocks/CU).
// HW pairs dispatch slots f and f+256 on one CU; remap (y,x) so those pairs have
// complementary causal lengths (32-2x) + (2x+2) = 34 chunk-units per CU.
__global__ __launch_bounds__(256, 2) void attn_kern(const BF* __restrict__ qb,
                                                    const BF* __restrict__ kb,
                                                    const BF* __restrict__ vT,
                                                    BF* __restrict__ o) {
  const int yy = blockIdx.y;
  const bool second = yy >= 16;
  const int bh = second ? ((yy - 16) * 2 + 1) : (yy * 2);
  const int qt = second ? (int)blockIdx.x : (15 - (int)blockIdx.x);
  const int q0 = qt * 128;
  const int tid = threadIdx.x;
  const int w = tid >> 6, l = tid & 63;
  const int lo5 = l & 31;
  const int hi = l >> 5;
  const int l7 = l & 7;

  // buffer b: Ks (64x192x2B = 24576) at b*40960, Vs (128x64x2B) at b*40960+24576
  __shared__ __align__(16) char smem[81920];

  const int q = q0 + w * 32 + lo5;   // this lane's q-row
  const int qmax = q0 + w * 32 + 31; // wave-uniform

  // Q fragments: B-operand, 12 k-steps of 16 (D=192)
  bf16x8 aq[12];
  {
    const BF* qrow = qb + ((size_t)bh * 2048 + q) * 192;
#pragma unroll
    for (int kst = 0; kst < 12; kst++)
      aq[kst] = *reinterpret_cast<const bf16x8*>(qrow + kst * 16 + hi * 8);
  }

  f32x16 Oacc[4];
#pragma unroll
  for (int dt = 0; dt < 4; dt++)
#pragma unroll
    for (int r = 0; r < 16; r++) Oacc[dt][r] = 0.f;
  float mrow = -3e38f, lrow = 0.f;

  const float scale = 0.07216878364870323f;  // 1/sqrt(192)
  const int nch = (q0 + 128) >> 6;

  auto STAGE = [&](int buf, int ch) {
    const int cc = ch << 6;
    BF* Ks = (BF*)(smem + buf * 40960);
    BF* Vs = (BF*)(smem + buf * 40960 + 24576);
#pragma unroll
    for (int j2 = 0; j2 < 6; j2++) {
      int D = tid + j2 * 256;
      int row = D / 24, sp = D % 24;
      int sl = sp ^ (row & 7);
      gload16(kb + ((size_t)bh * 2048 + cc + row) * 192 + sl * 8, Ks + D * 8);
    }
#pragma unroll
    for (int j2 = 0; j2 < 4; j2++) {
      int D = tid + j2 * 256;
      int row = D >> 3, sp = D & 7;
      int sl = sp ^ (row & 7);
      gload16(vT + ((size_t)bh * 128 + row) * 2048 + cc + sl * 8, Vs + D * 8);
    }
  };

  STAGE(0, 0);
  __syncthreads();  // drains vmcnt(0): chunk 0 staged

  for (int ch = 0; ch < nch; ch++) {
    const int c0 = ch << 6;
    const int cur = ch & 1;
    if (ch + 1 < nch) STAGE(cur ^ 1, ch + 1);  // issue next-chunk loads FIRST
    __builtin_amdgcn_sched_barrier(0);         // pin issue before compute
    BF* Ks = (BF*)(smem + cur * 40960);
    BF* Vs = (BF*)(smem + cur * 40960 + 24576);

    // QK^T (swapped): sf[t] = S^T[key tile t][q], 2 tiles x 12 ksteps
    f32x16 sf[2];
    __builtin_amdgcn_s_setprio(1);
#pragma unroll
    for (int t = 0; t < 2; t++) {
      if (c0 + t * 32 <= qmax) {
        f32x16 a0, a1;
#pragma unroll
        for (int r = 0; r < 16; r++) { a0[r] = 0.f; a1[r] = 0.f; }
#pragma unroll
        for (int kst = 0; kst < 12; kst++) {
          bf16x8 kfr = *reinterpret_cast<const bf16x8*>(
              Ks + (t * 32 + lo5) * 192 + (((kst * 2 + hi) ^ l7) * 8));
          if (kst & 1) a1 = mfma32(kfr, aq[kst], a1);
          else         a0 = mfma32(kfr, aq[kst], a0);
        }
        sf[t] = a0 + a1;
      } else {
#pragma unroll
        for (int r = 0; r < 16; r++) sf[t][r] = 0.f;
      }
    }
    __builtin_amdgcn_s_setprio(0);

    // scale + causal mask + in-lane max (keys: t*32+(r&3)+8*(r>>2)+4*hi)
    float mx = -3e38f;
#pragma unroll
    for (int t = 0; t < 2; t++) {
#pragma unroll
      for (int r = 0; r < 16; r++) {
        int key = c0 + t * 32 + (r & 3) + 8 * (r >> 2) + 4 * hi;
        float v = sf[t][r] * scale;
        v = (key <= q) ? v : -1e30f;
        sf[t][r] = v;
        mx = fmaxf(mx, v);
      }
    }
    mx = fmaxf(mx, __shfl_xor(mx, 32, 64));  // combine complementary key halves
    float mnew = fmaxf(mrow, mx);
    float corr = __expf(mrow - mnew);
    mrow = mnew;
    float psum = 0.f;
#pragma unroll
    for (int t = 0; t < 2; t++)
#pragma unroll
      for (int r = 0; r < 16; r++) {
        float p = __expf(sf[t][r] - mnew);
        sf[t][r] = p;
        psum += p;
      }
    psum += __shfl_xor(psum, 32, 64);
    lrow = lrow * corr + psum;
#pragma unroll
    for (int dt = 0; dt < 4; dt++) Oacc[dt] *= corr;

    // P -> bf16 B-frags, in-register: cvt_pk + permlane32_swap
    bf16x8 pb[4];
#pragma unroll
    for (int ks = 0; ks < 4; ks++) {
      if (c0 + ks * 16 > qmax) continue;
      int t = ks >> 1, base = (ks & 1) * 8;
      unsigned Xa = cvtpk(sf[t][base + 0], sf[t][base + 1]);
      unsigned Xb = cvtpk(sf[t][base + 2], sf[t][base + 3]);
      unsigned Ya = cvtpk(sf[t][base + 4], sf[t][base + 5]);
      unsigned Yb = cvtpk(sf[t][base + 6], sf[t][base + 7]);
      plswap(Xa, Ya, hi != 0);
      plswap(Xb, Yb, hi != 0);
      union { unsigned u[4]; bf16x8 v; } pk_;
      pk_.u[0] = Xa; pk_.u[1] = Xb; pk_.u[2] = Ya; pk_.u[3] = Yb;
      pb[ks] = pk_.v;
    }

    // PV: O^T[d][q] += V x P, 4 d-tiles x 4 ksteps
    __builtin_amdgcn_s_setprio(1);
#pragma unroll
    for (int ks = 0; ks < 4; ks++) {
      if (c0 + ks * 16 > qmax) continue;
#pragma unroll
      for (int dt = 0; dt < 4; dt++) {
        bf16x8 vfr = *reinterpret_cast<const bf16x8*>(
            Vs + (dt * 32 + lo5) * 64 + (((ks * 2 + hi) ^ l7) * 8));
        Oacc[dt] = mfma32(vfr, pb[ks], Oacc[dt]);
      }
    }
    __builtin_amdgcn_s_setprio(0);
    __syncthreads();  // next buffer staged + all waves done reading cur
  }

  // epilogue: normalize (lane-local l), transpose via LDS, coalesced store
  BF* Osh = (BF*)smem;  // [128 rows][136 elems]
  float rinv = 1.0f / lrow;
  const int orow = w * 32 + lo5;
#pragma unroll
  for (int dt = 0; dt < 4; dt++) {
#pragma unroll
    for (int g = 0; g < 4; g++) {
      unsigned d0 = cvtpk(Oacc[dt][g * 4 + 0] * rinv, Oacc[dt][g * 4 + 1] * rinv);
      unsigned d1 = cvtpk(Oacc[dt][g * 4 + 2] * rinv, Oacc[dt][g * 4 + 3] * rinv);
      uint2 pr; pr.x = d0; pr.y = d1;
      *reinterpret_cast<uint2*>(Osh + orow * 136 + dt * 32 + g * 8 + hi * 4) = pr;
    }
  }
  __syncthreads();
  const int b = bh >> 4, h = bh & 15;
  const int cb = tid & 15, rb = tid >> 4;
#pragma unroll
  for (int rr = 0; rr < 8; rr++) {
    int row = rb + rr * 16;
    bf16x8 v = *reinterpret_cast<const bf16x8*>(Osh + row * 136 + cb * 8);
    *reinterpret_cast<bf16x8*>(o + ((size_t)(b * 2048 + q0 + row)) * 2048 + h * 128 + cb * 8) = v;
  }
}

extern "C" void kernel_launch(void* const* d_in, const int* in_sizes, int n_in,
                              void* d_out, int out_size, void* d_ws, size_t ws_size,
                              hipStream_t stream) {
  const float* hs   = (const float*)d_in[0];
  const float* wDKV = (const float*)d_in[2];
  const float* wUK  = (const float*)d_in[3];
  const float* wUV  = (const float*)d_in[4];
  const float* wDQ  = (const float*)d_in[5];
  const float* wUQ  = (const float*)d_in[6];
  const float* wQR  = (const float*)d_in[7];
  const float* wKR  = (const float*)d_in[8];
  const float* wO   = (const float*)d_in[9];
  float* out = (float*)d_out;

  char* ws = (char*)d_ws;
  size_t off = 0;
  auto alloc = [&](size_t bytes) -> char* {
    char* p = ws + off;
    off += (bytes + 255) & ~(size_t)255;
    return p;
  };
  BF* hsb   = (BF*)alloc((size_t)M_ * HID_ * 2);          // 4096x2048
  BF* tCat1 = (BF*)alloc((size_t)1664 * HID_ * 2);        // [DKV;DQ;KRpad] x 2048
  BF* tCat2 = (BF*)alloc((size_t)4096 * CKV_ * 2);        // [UK;UV] x 512
  BF* tCat3 = (BF*)alloc((size_t)3072 * CQ_ * 2);         // [UQ;QR] x 1024
  BF* tWO   = (BF*)alloc((size_t)HID_ * (NH_*HD_) * 2);   // (2048,2048)
  BF* cKV   = (BF*)alloc((size_t)M_ * CKV_ * 2);
  BF* cQ    = (BF*)alloc((size_t)M_ * CQ_ * 2);
  BF* qbuf  = (BF*)alloc((size_t)B_ * NH_ * S_ * DQK_ * 2);
  BF* kbuf  = (BF*)alloc((size_t)B_ * NH_ * S_ * DQK_ * 2);
  BF* vTb   = (BF*)alloc((size_t)B_ * NH_ * HD_ * S_ * 2);
  BF* qRt   = (BF*)alloc((size_t)M_ * (NH_*RD_) * 2);
  BF* kRt   = (BF*)alloc((size_t)M_ * 128 * 2);
  BF* aout  = (BF*)alloc((size_t)M_ * (NH_*HD_) * 2);

  // 1. hidden -> bf16
  f2b_kern<<<(M_ * HID_ / 4 + 255) / 256, 256, 0, stream>>>(hs, hsb, M_ * HID_ / 4);

  // 2. weight transposes into concatenated B^T panels
  dim3 tb(32, 8);
  wtrans<<<dim3(512 / 32, HID_ / 32), tb, 0, stream>>>(wDKV, tCat1, HID_, 512, 512);
  wtrans<<<dim3(1024 / 32, HID_ / 32), tb, 0, stream>>>(wDQ, tCat1 + (size_t)512 * HID_, HID_, 1024, 1024);
  wtrans<<<dim3(128 / 32, HID_ / 32), tb, 0, stream>>>(wKR, tCat1 + (size_t)1536 * HID_, HID_, 64, 128);
  wtrans<<<dim3(2048 / 32, CKV_ / 32), tb, 0, stream>>>(wUK, tCat2, CKV_, 2048, 2048);
  wtrans<<<dim3(2048 / 32, CKV_ / 32), tb, 0, stream>>>(wUV, tCat2 + (size_t)2048 * CKV_, CKV_, 2048, 2048);
  wtrans<<<dim3(2048 / 32, CQ_ / 32), tb, 0, stream>>>(wUQ, tCat3, CQ_, 2048, 2048);
  wtrans<<<dim3(1024 / 32, CQ_ / 32), tb, 0, stream>>>(wQR, tCat3 + (size_t)2048 * CQ_, CQ_, 1024, 1024);
  wtrans<<<dim3(2048 / 32, HID_ / 32), tb, 0, stream>>>(wO, tWO, HID_, 2048, 2048);

  // 3. fused projections
  gemm_f<1><<<dim3(1664 / 128, M_ / 128), 256, 0, stream>>>(hsb, tCat1, cKV, cQ, kRt, M_, 1664, HID_);
  gemm_f<3><<<dim3(3072 / 128, M_ / 128), 256, 0, stream>>>(cQ, tCat3, qbuf, qRt, nullptr, M_, 3072, CQ_);
  gemm_f<2><<<dim3(4096 / 128, M_ / 128), 256, 0, stream>>>(cKV, tCat2, kbuf, vTb, nullptr, M_, 4096, CKV_);

  // 4. RoPE
  rope_q<<<(M_ * NH_ * RD_) / 256, 256, 0, stream>>>(qRt, qbuf);
  rope_k<<<(M_ * RD_) / 256, 256, 0, stream>>>(kRt, kbuf);

  // 5. attention (QBLK=128, KVBLK=64, 32x32 MFMA, in-register P, complementary pairing)
  attn_kern<<<dim3(S_ / 128, B_ * NH_), 256, 0, stream>>>(qbuf, kbuf, vTb, aout);

  // 6. output projection (fp32 out)
  gemm_f<4><<<dim3(2048 / 128, M_ / 128), 256, 0, stream>>>(aout, tWO, out, nullptr, nullptr, M_, 2048, HID_);
}